// Round 1
// baseline (40542.163 us; speedup 1.0000x reference)
//
#include <hip/hip_runtime.h>
#include <hip/hip_bf16.h>

// ---- problem constants ----
#define BB   8
#define SS   512
#define HH   768
#define LL   12
#define NHH  12
#define DHH  64
#define FFF  3072
#define VV   21128
#define PAD_ID 0
#define SEP_ID 102
#define BS   (BB*SS)          // 4096
#define BSH  (BS*HH)          // 3,145,728
#define BSFF ((size_t)BS*FFF) // 12,582,912

// ---------------------------------------------------------------------------
// block reduction helpers (256 threads)
// ---------------------------------------------------------------------------
__device__ __forceinline__ float block_reduce_sum(float v, float* red, int tid) {
    red[tid] = v; __syncthreads();
    for (int off = 128; off > 0; off >>= 1) {
        if (tid < off) red[tid] += red[tid + off];
        __syncthreads();
    }
    float r = red[0]; __syncthreads();
    return r;
}

__device__ __forceinline__ float block_reduce_max(float v, float* red, int tid) {
    red[tid] = v; __syncthreads();
    for (int off = 128; off > 0; off >>= 1) {
        if (tid < off) red[tid] = fmaxf(red[tid], red[tid + off]);
        __syncthreads();
    }
    float r = red[0]; __syncthreads();
    return r;
}

// ---------------------------------------------------------------------------
// qlen[b] = (first index j with ids[b,j]==SEP, else 0) + 1
// ---------------------------------------------------------------------------
__global__ void __launch_bounds__(256) qlen_kernel(const int* __restrict__ ids,
                                                   int* __restrict__ qlen) {
    int b = blockIdx.x, tid = threadIdx.x;
    __shared__ int red[256];
    int best = 1 << 30;
    for (int j = tid; j < SS; j += 256)
        if (ids[b * SS + j] == SEP_ID) best = min(best, j);
    red[tid] = best; __syncthreads();
    for (int off = 128; off > 0; off >>= 1) {
        if (tid < off) red[tid] = min(red[tid], red[tid + off]);
        __syncthreads();
    }
    if (tid == 0) qlen[b] = (red[0] == (1 << 30) ? 0 : red[0]) + 1;
}

// ---------------------------------------------------------------------------
// embedding gather + LayerNorm  (one block per token, 256 thr, H=768 -> 3/thr)
// ---------------------------------------------------------------------------
__global__ void __launch_bounds__(256) embed_ln_kernel(
    const int* __restrict__ ids, const float* __restrict__ we,
    const float* __restrict__ pe, const float* __restrict__ te,
    const float* __restrict__ g, const float* __restrict__ bt,
    float* __restrict__ h) {
    int token = blockIdx.x, tid = threadIdx.x;
    int s = token % SS;
    int id = ids[token];
    __shared__ float red[256];
    float x[3];
#pragma unroll
    for (int i = 0; i < 3; ++i) {
        int idx = tid + i * 256;
        x[i] = we[(size_t)id * HH + idx] + pe[(size_t)s * HH + idx] + te[idx];
    }
    float sum = x[0] + x[1] + x[2];
    sum = block_reduce_sum(sum, red, tid);
    float mu = sum * (1.0f / HH);
    float vs = 0.f;
#pragma unroll
    for (int i = 0; i < 3; ++i) { float d = x[i] - mu; vs += d * d; }
    vs = block_reduce_sum(vs, red, tid);
    float rstd = rsqrtf(vs * (1.0f / HH) + 1e-12f);
    size_t base = (size_t)token * HH;
#pragma unroll
    for (int i = 0; i < 3; ++i) {
        int idx = tid + i * 256;
        h[base + idx] = (x[i] - mu) * rstd * g[idx] + bt[idx];
    }
}

// ---------------------------------------------------------------------------
// h = LN(h + proj)   (one block per token)
// ---------------------------------------------------------------------------
__global__ void __launch_bounds__(256) add_ln_kernel(
    float* __restrict__ h, const float* __restrict__ proj,
    const float* __restrict__ g, const float* __restrict__ bt) {
    int token = blockIdx.x, tid = threadIdx.x;
    __shared__ float red[256];
    size_t base = (size_t)token * HH;
    float x[3];
#pragma unroll
    for (int i = 0; i < 3; ++i) {
        int idx = tid + i * 256;
        x[i] = h[base + idx] + proj[base + idx];
    }
    float sum = x[0] + x[1] + x[2];
    sum = block_reduce_sum(sum, red, tid);
    float mu = sum * (1.0f / HH);
    float vs = 0.f;
#pragma unroll
    for (int i = 0; i < 3; ++i) { float d = x[i] - mu; vs += d * d; }
    vs = block_reduce_sum(vs, red, tid);
    float rstd = rsqrtf(vs * (1.0f / HH) + 1e-12f);
#pragma unroll
    for (int i = 0; i < 3; ++i) {
        int idx = tid + i * 256;
        h[base + idx] = (x[i] - mu) * rstd * g[idx] + bt[idx];
    }
}

// ---------------------------------------------------------------------------
// fp32 GEMM: C[M,N] = A[M,K] @ B[K,N] + bias[N]  (optional exact GELU)
// 128x128 tile, BK=8, 256 threads, 8x8 accumulators/thread.
// Only N may be non-multiple-of-128 (classifier tail).
// ---------------------------------------------------------------------------
#define BM 128
#define BN 128
#define BKK 8

__global__ void __launch_bounds__(256) gemm_bias_kernel(
    const float* __restrict__ A, const float* __restrict__ Bw,
    const float* __restrict__ bias, float* __restrict__ C,
    int M, int N, int K, int act /*0 none, 1 gelu*/) {
    __shared__ float As[BKK][BM + 4];   // stride 132 floats (528B, 16B-mult)
    __shared__ float Bs[BKK][BN + 4];

    int tid = threadIdx.x;
    int tx = tid & 15, ty = tid >> 4;
    const int mBase = ty * 8, nBase = tx * 8;
    int n0 = blockIdx.x * BN;
    int m0 = blockIdx.y * BM;

    int aRow = tid >> 1;            // 0..127
    int aK   = (tid & 1) * 4;       // 0 or 4
    int bRow = tid >> 5;            // 0..7
    int bCol = (tid & 31) * 4;      // 0..124

    float acc[8][8];
#pragma unroll
    for (int i = 0; i < 8; ++i)
#pragma unroll
        for (int j = 0; j < 8; ++j) acc[i][j] = 0.f;

    const float* Aptr = A + (size_t)(m0 + aRow) * K + aK;

    for (int k0 = 0; k0 < K; k0 += BKK) {
        // stage A (128 rows x 8 k), transposed into As[k][m]
        float4 av = *(const float4*)(Aptr + k0);
        As[aK + 0][aRow] = av.x;
        As[aK + 1][aRow] = av.y;
        As[aK + 2][aRow] = av.z;
        As[aK + 3][aRow] = av.w;
        // stage B (8 k x 128 n)
        {
            int n = n0 + bCol;
            const float* bp = Bw + (size_t)(k0 + bRow) * N + n;
            float4 bv;
            if (n + 3 < N) {
                bv = *(const float4*)bp;
            } else {
                bv.x = (n + 0 < N) ? bp[0] : 0.f;
                bv.y = (n + 1 < N) ? bp[1] : 0.f;
                bv.z = (n + 2 < N) ? bp[2] : 0.f;
                bv.w = (n + 3 < N) ? bp[3] : 0.f;
            }
            *(float4*)&Bs[bRow][bCol] = bv;
        }
        __syncthreads();
#pragma unroll
        for (int kk = 0; kk < BKK; ++kk) {
            float4 a0 = *(const float4*)&As[kk][mBase];
            float4 a1 = *(const float4*)&As[kk][mBase + 4];
            float4 b0 = *(const float4*)&Bs[kk][nBase];
            float4 b1 = *(const float4*)&Bs[kk][nBase + 4];
            float ar[8] = {a0.x, a0.y, a0.z, a0.w, a1.x, a1.y, a1.z, a1.w};
            float br[8] = {b0.x, b0.y, b0.z, b0.w, b1.x, b1.y, b1.z, b1.w};
#pragma unroll
            for (int i = 0; i < 8; ++i)
#pragma unroll
                for (int j = 0; j < 8; ++j) acc[i][j] += ar[i] * br[j];
        }
        __syncthreads();
    }

    // epilogue
    bool fullN = (n0 + BN <= N);
    float bb[8];
#pragma unroll
    for (int j = 0; j < 8; ++j) {
        int n = n0 + nBase + j;
        bb[j] = (n < N) ? bias[n] : 0.f;
    }
#pragma unroll
    for (int i = 0; i < 8; ++i) {
        int m = m0 + mBase + i;
        float* crow = C + (size_t)m * N + n0 + nBase;
        float out[8];
#pragma unroll
        for (int j = 0; j < 8; ++j) {
            float v = acc[i][j] + bb[j];
            if (act == 1) v = 0.5f * v * (1.0f + erff(v * 0.70710678118654752f));
            out[j] = v;
        }
        if (fullN) {
            float4 o0 = {out[0], out[1], out[2], out[3]};
            float4 o1 = {out[4], out[5], out[6], out[7]};
            *(float4*)(crow + 0) = o0;
            *(float4*)(crow + 4) = o1;
        } else {
#pragma unroll
            for (int j = 0; j < 8; ++j)
                if (n0 + nBase + j < N) crow[j] = out[j];
        }
    }
}

// ---------------------------------------------------------------------------
// attention: one block per (q-position, head, batch). Full row of scores in
// LDS, softmax, then weighted sum of V. q/k/v layout: [B,S,H] head-interleaved.
// ---------------------------------------------------------------------------
__global__ void __launch_bounds__(256) attn_kernel(
    const float* __restrict__ q, const float* __restrict__ k,
    const float* __restrict__ v, const int* __restrict__ ids,
    const int* __restrict__ qlen, float* __restrict__ att) {
    int s_q = blockIdx.x, hh = blockIdx.y, b = blockIdx.z;
    int tid = threadIdx.x;
    __shared__ float qv[DHH];
    __shared__ float sc[SS];
    __shared__ float red[256];

    const float* qrow = q + ((size_t)b * SS + s_q) * HH + hh * DHH;
    if (tid < DHH) qv[tid] = qrow[tid];
    __syncthreads();

    int ql = qlen[b];
    bool pad_q = (ids[b * SS + s_q] != PAD_ID);

    // scores
    for (int j = tid; j < SS; j += 256) {
        const float4* krow =
            (const float4*)(k + ((size_t)b * SS + j) * HH + hh * DHH);
        float d = 0.f;
#pragma unroll
        for (int e = 0; e < DHH / 4; ++e) {
            float4 kv = krow[e];
            d += qv[e * 4 + 0] * kv.x + qv[e * 4 + 1] * kv.y +
                 qv[e * 4 + 2] * kv.z + qv[e * 4 + 3] * kv.w;
        }
        bool pad_j = (ids[b * SS + j] != PAD_ID);
        bool in_ans = (s_q >= ql) && (j >= ql);
        bool ok = pad_q && pad_j && (!in_ans || (j <= s_q));
        sc[j] = d * 0.125f + (ok ? 0.0f : -1e9f);
    }
    __syncthreads();

    // softmax (unnormalized exp in sc, normalize at the end)
    float m = -INFINITY;
    for (int j = tid; j < SS; j += 256) m = fmaxf(m, sc[j]);
    m = block_reduce_max(m, red, tid);

    float ssum = 0.f;
    for (int j = tid; j < SS; j += 256) {
        float e = expf(sc[j] - m);
        sc[j] = e;
        ssum += e;
    }
    ssum = block_reduce_sum(ssum, red, tid);
    float inv = 1.0f / ssum;
    __syncthreads();

    // ctx[d] = sum_j p_j * v[j][d] ; 256 thr = 64 d x 4 j-groups
    int d = tid & 63, jg = tid >> 6;
    const float* vbase = v + (size_t)b * SS * HH + hh * DHH + d;
    float cacc = 0.f;
    for (int j = jg * 128; j < (jg + 1) * 128; ++j)
        cacc += sc[j] * vbase[(size_t)j * HH];
    red[tid] = cacc; __syncthreads();
    if (tid < 64) {
        float r = (red[tid] + red[tid + 64]) + (red[tid + 128] + red[tid + 192]);
        att[((size_t)b * SS + s_q) * HH + hh * DHH + tid] = r * inv;
    }
}

// ---------------------------------------------------------------------------
// launch
// ---------------------------------------------------------------------------
extern "C" void kernel_launch(void* const* d_in, const int* in_sizes, int n_in,
                              void* d_out, int out_size, void* d_ws, size_t ws_size,
                              hipStream_t stream) {
    const int*   ids      = (const int*)d_in[0];
    const float* word_emb = (const float*)d_in[1];
    const float* pos_emb  = (const float*)d_in[2];
    const float* type_emb = (const float*)d_in[3];
    const float* emb_ln_g = (const float*)d_in[4];
    const float* emb_ln_b = (const float*)d_in[5];
    const float* attn_w   = (const float*)d_in[6];
    const float* attn_b   = (const float*)d_in[7];
    const float* ln1_g    = (const float*)d_in[8];
    const float* ln1_b    = (const float*)d_in[9];
    const float* ffn_w1   = (const float*)d_in[10];
    const float* ffn_b1   = (const float*)d_in[11];
    const float* ffn_w2   = (const float*)d_in[12];
    const float* ffn_b2   = (const float*)d_in[13];
    const float* ln2_g    = (const float*)d_in[14];
    const float* ln2_b    = (const float*)d_in[15];
    const float* cls_w    = (const float*)d_in[16];
    const float* cls_b    = (const float*)d_in[17];
    float* out = (float*)d_out;

    float* ws  = (float*)d_ws;
    float* h   = ws;                 // [BS,H]
    float* qb  = h + BSH;            // [BS,H]  (also reused as proj buffer)
    float* kb  = qb + BSH;
    float* vb  = kb + BSH;
    float* att = vb + BSH;
    float* ff  = att + BSH;          // [BS,FF]
    int*   qlen = (int*)(ff + BSFF); // [B]

    qlen_kernel<<<BB, 256, 0, stream>>>(ids, qlen);
    embed_ln_kernel<<<BS, 256, 0, stream>>>(ids, word_emb, pos_emb, type_emb,
                                            emb_ln_g, emb_ln_b, h);

    dim3 gProj((HH + BN - 1) / BN, BS / BM);        // 6 x 32
    dim3 gFF1((FFF + BN - 1) / BN, BS / BM);        // 24 x 32
    dim3 gCls((VV + BN - 1) / BN, BS / BM);         // 166 x 32
    dim3 gAttn(SS, NHH, BB);

    for (int l = 0; l < LL; ++l) {
        const float* wq = attn_w + (size_t)l * 4 * HH * HH;
        const float* wk = wq + (size_t)HH * HH;
        const float* wv = wk + (size_t)HH * HH;
        const float* wo = wv + (size_t)HH * HH;
        const float* bq = attn_b + (size_t)l * 4 * HH;
        const float* bk = bq + HH;
        const float* bv = bk + HH;
        const float* bo = bv + HH;

        gemm_bias_kernel<<<gProj, 256, 0, stream>>>(h, wq, bq, qb, BS, HH, HH, 0);
        gemm_bias_kernel<<<gProj, 256, 0, stream>>>(h, wk, bk, kb, BS, HH, HH, 0);
        gemm_bias_kernel<<<gProj, 256, 0, stream>>>(h, wv, bv, vb, BS, HH, HH, 0);

        attn_kernel<<<gAttn, 256, 0, stream>>>(qb, kb, vb, ids, qlen, att);

        gemm_bias_kernel<<<gProj, 256, 0, stream>>>(att, wo, bo, qb, BS, HH, HH, 0);
        add_ln_kernel<<<BS, 256, 0, stream>>>(h, qb, ln1_g + (size_t)l * HH,
                                              ln1_b + (size_t)l * HH);

        gemm_bias_kernel<<<gFF1, 256, 0, stream>>>(h, ffn_w1 + (size_t)l * HH * FFF,
                                                   ffn_b1 + (size_t)l * FFF, ff,
                                                   BS, FFF, HH, 1);
        gemm_bias_kernel<<<gProj, 256, 0, stream>>>(ff, ffn_w2 + (size_t)l * FFF * HH,
                                                    ffn_b2 + (size_t)l * HH, qb,
                                                    BS, HH, FFF, 0);
        add_ln_kernel<<<BS, 256, 0, stream>>>(h, qb, ln2_g + (size_t)l * HH,
                                              ln2_b + (size_t)l * HH);
    }

    gemm_bias_kernel<<<gCls, 256, 0, stream>>>(h, cls_w, cls_b, out, BS, VV, HH, 0);
}

// Round 2
// 4266.263 us; speedup vs baseline: 9.5030x; 9.5030x over previous
//
#include <hip/hip_runtime.h>
#include <hip/hip_bf16.h>
#include <stdint.h>

// ---- problem constants ----
#define BB   8
#define SS   512
#define HH   768
#define LL   12
#define NHH  12
#define DHH  64
#define FFF  3072
#define VV   21128
#define PAD_ID 0
#define SEP_ID 102
#define BS   (BB*SS)              // 4096
#define BSH  ((size_t)BS*HH)      // 3,145,728
#define BSFF ((size_t)BS*FFF)     // 12,582,912

using bf16 = __hip_bfloat16;
typedef __attribute__((ext_vector_type(8))) short short8;
typedef __attribute__((ext_vector_type(4))) float f32x4;

__device__ __forceinline__ f32x4 Z4() { f32x4 z = {0.f, 0.f, 0.f, 0.f}; return z; }

// async global->LDS, 16B per lane. LDS dest must be wave-uniform base + lane*16.
__device__ __forceinline__ void gload16(void* lds, const void* g) {
    __builtin_amdgcn_global_load_lds(
        (const __attribute__((address_space(1))) uint32_t*)g,
        (__attribute__((address_space(3))) uint32_t*)(uint32_t)(uintptr_t)lds,
        16, 0, 0);
}

// ---------------------------------------------------------------------------
// qlen[b] = (first j with ids[b,j]==SEP else 0) + 1
// ---------------------------------------------------------------------------
__global__ void __launch_bounds__(256) qlen_kernel(const int* __restrict__ ids,
                                                   int* __restrict__ qlen) {
    int b = blockIdx.x, tid = threadIdx.x;
    __shared__ int red[256];
    int best = 1 << 30;
    for (int j = tid; j < SS; j += 256)
        if (ids[b * SS + j] == SEP_ID) best = min(best, j);
    red[tid] = best; __syncthreads();
    for (int off = 128; off > 0; off >>= 1) {
        if (tid < off) red[tid] = min(red[tid], red[tid + off]);
        __syncthreads();
    }
    if (tid == 0) qlen[b] = (red[0] == (1 << 30) ? 0 : red[0]) + 1;
}

// ---------------------------------------------------------------------------
// block reduce (256 thr)
// ---------------------------------------------------------------------------
__device__ __forceinline__ float block_reduce_sum(float v, float* red, int tid) {
    red[tid] = v; __syncthreads();
    for (int off = 128; off > 0; off >>= 1) {
        if (tid < off) red[tid] += red[tid + off];
        __syncthreads();
    }
    float r = red[0]; __syncthreads();
    return r;
}

// ---------------------------------------------------------------------------
// embedding gather + LN  -> h (f32) and hb (bf16)
// ---------------------------------------------------------------------------
__global__ void __launch_bounds__(256) embed_ln_kernel(
    const int* __restrict__ ids, const float* __restrict__ we,
    const float* __restrict__ pe, const float* __restrict__ te,
    const float* __restrict__ g, const float* __restrict__ bt,
    float* __restrict__ h, bf16* __restrict__ hb) {
    int token = blockIdx.x, tid = threadIdx.x;
    int s = token % SS;
    int id = ids[token];
    __shared__ float red[256];
    float x[3];
#pragma unroll
    for (int i = 0; i < 3; ++i) {
        int idx = tid + i * 256;
        x[i] = we[(size_t)id * HH + idx] + pe[(size_t)s * HH + idx] + te[idx];
    }
    float sum = block_reduce_sum(x[0] + x[1] + x[2], red, tid);
    float mu = sum * (1.0f / HH);
    float vs = 0.f;
#pragma unroll
    for (int i = 0; i < 3; ++i) { float d = x[i] - mu; vs += d * d; }
    vs = block_reduce_sum(vs, red, tid);
    float rstd = rsqrtf(vs * (1.0f / HH) + 1e-12f);
    size_t base = (size_t)token * HH;
#pragma unroll
    for (int i = 0; i < 3; ++i) {
        int idx = tid + i * 256;
        float v = (x[i] - mu) * rstd * g[idx] + bt[idx];
        h[base + idx] = v;
        hb[base + idx] = __float2bfloat16(v);
    }
}

// ---------------------------------------------------------------------------
// h = LN(h + proj)  -> h (f32) and hb (bf16)
// ---------------------------------------------------------------------------
__global__ void __launch_bounds__(256) add_ln_kernel(
    float* __restrict__ h, const float* __restrict__ proj,
    const float* __restrict__ g, const float* __restrict__ bt,
    bf16* __restrict__ hb) {
    int token = blockIdx.x, tid = threadIdx.x;
    __shared__ float red[256];
    size_t base = (size_t)token * HH;
    float x[3];
#pragma unroll
    for (int i = 0; i < 3; ++i) {
        int idx = tid + i * 256;
        x[i] = h[base + idx] + proj[base + idx];
    }
    float sum = block_reduce_sum(x[0] + x[1] + x[2], red, tid);
    float mu = sum * (1.0f / HH);
    float vs = 0.f;
#pragma unroll
    for (int i = 0; i < 3; ++i) { float d = x[i] - mu; vs += d * d; }
    vs = block_reduce_sum(vs, red, tid);
    float rstd = rsqrtf(vs * (1.0f / HH) + 1e-12f);
#pragma unroll
    for (int i = 0; i < 3; ++i) {
        int idx = tid + i * 256;
        float v = (x[i] - mu) * rstd * g[idx] + bt[idx];
        h[base + idx] = v;
        hb[base + idx] = __float2bfloat16(v);
    }
}

// ---------------------------------------------------------------------------
// transpose-convert: in f32 [K][N] (row-major) -> out bf16 [N][K]
// z = matrix index (strided)
// ---------------------------------------------------------------------------
__global__ void __launch_bounds__(256) transp_conv(
    const float* __restrict__ in, bf16* __restrict__ out,
    int K, int N, size_t inStride, size_t outStride) {
    const float* src = in + (size_t)blockIdx.z * inStride;
    bf16* dst = out + (size_t)blockIdx.z * outStride;
    __shared__ float t[64][65];
    int n0 = blockIdx.x * 64, k0 = blockIdx.y * 64;
    int tid = threadIdx.x;
#pragma unroll
    for (int i = 0; i < 16; ++i) {
        int lin = tid + i * 256;
        int r = lin >> 6, c = lin & 63;
        int kk = k0 + r, nn = n0 + c;
        t[r][c] = (kk < K && nn < N) ? src[(size_t)kk * N + nn] : 0.f;
    }
    __syncthreads();
#pragma unroll
    for (int i = 0; i < 16; ++i) {
        int lin = tid + i * 256;
        int r = lin >> 6, c = lin & 63;
        int nn = n0 + r, kk = k0 + c;
        if (nn < N && kk < K)
            dst[(size_t)nn * K + kk] = __float2bfloat16(t[c][r]);
    }
}

// ---------------------------------------------------------------------------
// v [BS][H] bf16 -> vT [B][NH][DH][S] bf16
// ---------------------------------------------------------------------------
__global__ void __launch_bounds__(256) vtrans_kernel(const bf16* __restrict__ v,
                                                     bf16* __restrict__ vT) {
    __shared__ bf16 t[64][66];
    int s0 = blockIdx.x * 64, h = blockIdx.y, b = blockIdx.z;
    int tid = threadIdx.x;
#pragma unroll
    for (int i = 0; i < 16; ++i) {
        int lin = tid + i * 256;
        int sr = lin >> 6, dc = lin & 63;
        t[sr][dc] = v[((size_t)(b * SS + s0 + sr)) * HH + h * 64 + dc];
    }
    __syncthreads();
#pragma unroll
    for (int i = 0; i < 16; ++i) {
        int lin = tid + i * 256;
        int dr = lin >> 6, sc = lin & 63;
        vT[(((size_t)(b * NHH + h)) * 64 + dr) * SS + s0 + sc] = t[sc][dr];
    }
}

// ---------------------------------------------------------------------------
// bf16 MFMA GEMM (m97 structure): C[M,N] = A[M,K] @ BT[N,K]^T + bias
// 128x128 tile, BK=32, 4 waves, 16x16x32 MFMA, global_load_lds staging.
// OUT_BF16: 1 -> bf16 C; ACT: 1 -> exact GELU.
// ---------------------------------------------------------------------------
#define GBM 128
#define GBN 128
#define GBK 32

template <int OUT_BF16, int ACT>
__global__ void __launch_bounds__(256) gemm_bf16_kernel(
    const bf16* __restrict__ A, const bf16* __restrict__ BT,
    const float* __restrict__ bias, void* __restrict__ Cout,
    int M, int N, int K) {
    __shared__ __align__(16) bf16 As[GBM * GBK];
    __shared__ __align__(16) bf16 Bs[GBN * GBK];
    int tid = threadIdx.x;
    int lane = tid & 63, wid = tid >> 6;
    int m0 = blockIdx.y * GBM, n0 = blockIdx.x * GBN;
    int wr = (wid >> 1) * 64, wc = (wid & 1) * 64;

    f32x4 acc[4][4];
#pragma unroll
    for (int i = 0; i < 4; ++i)
#pragma unroll
        for (int j = 0; j < 4; ++j) acc[i][j] = Z4();

    const int lin0 = tid * 16;           // byte in 8KB tile, issue 0
    const int rowA0 = lin0 >> 6;         // 64B per row (32 bf16)
    const int colB = lin0 & 63;          // byte within row
    const int rowA1 = rowA0 + 64;
    const char* Abase = (const char*)A;
    const char* Bbase = (const char*)BT;

    for (int k0 = 0; k0 < K; k0 += GBK) {
        gload16((char*)As + lin0,
                Abase + ((size_t)(m0 + rowA0) * K + k0) * 2 + colB);
        gload16((char*)As + lin0 + 4096,
                Abase + ((size_t)(m0 + rowA1) * K + k0) * 2 + colB);
        int nr0 = n0 + rowA0; if (nr0 >= N) nr0 = N - 1;
        int nr1 = n0 + rowA1; if (nr1 >= N) nr1 = N - 1;
        gload16((char*)Bs + lin0,
                Bbase + ((size_t)nr0 * K + k0) * 2 + colB);
        gload16((char*)Bs + lin0 + 4096,
                Bbase + ((size_t)nr1 * K + k0) * 2 + colB);
        __syncthreads();   // drains vmcnt -> staged data visible

        short8 af[4], bfr[4];
#pragma unroll
        for (int i = 0; i < 4; ++i) {
            int ar = wr + i * 16 + (lane & 15);
            af[i] = *(const short8*)(As + ar * GBK + (lane >> 4) * 8);
            int br = wc + i * 16 + (lane & 15);
            bfr[i] = *(const short8*)(Bs + br * GBK + (lane >> 4) * 8);
        }
#pragma unroll
        for (int i = 0; i < 4; ++i)
#pragma unroll
            for (int j = 0; j < 4; ++j)
                acc[i][j] = __builtin_amdgcn_mfma_f32_16x16x32_bf16(
                    af[i], bfr[j], acc[i][j], 0, 0, 0);
        __syncthreads();   // all reads done before next staging
    }

    bool nfull = (n0 + GBN <= N);
#pragma unroll
    for (int i = 0; i < 4; ++i) {
#pragma unroll
        for (int r = 0; r < 4; ++r) {
            int m = m0 + wr + i * 16 + (lane >> 4) * 4 + r;
#pragma unroll
            for (int j = 0; j < 4; ++j) {
                int n = n0 + wc + j * 16 + (lane & 15);
                if (nfull || n < N) {
                    float v = acc[i][j][r] + bias[n];
                    if (ACT) v = 0.5f * v * (1.0f + erff(v * 0.70710678118654752f));
                    if (OUT_BF16)
                        ((bf16*)Cout)[(size_t)m * N + n] = __float2bfloat16(v);
                    else
                        ((float*)Cout)[(size_t)m * N + n] = v;
                }
            }
        }
    }
}

// ---------------------------------------------------------------------------
// flash attention, bf16 MFMA. Block = 64 q-rows (4 waves x 16), KV tiles of 64.
// Q,K: [BS][H] bf16 (head slice); VT: [B][NH][DH][S] bf16.  att out: [BS][H] bf16.
// All LDS tiles XOR-swizzled: byte_in_row ^= (row&7)<<4 (row stride 128B).
// ---------------------------------------------------------------------------
__global__ void __launch_bounds__(256) attn_mfma_kernel(
    const bf16* __restrict__ Q, const bf16* __restrict__ K,
    const bf16* __restrict__ VT, const int* __restrict__ ids,
    const int* __restrict__ qlen, bf16* __restrict__ att) {
    __shared__ __align__(16) bf16 Qs[64 * 64];
    __shared__ __align__(16) bf16 Ks[64 * 64];
    __shared__ __align__(16) bf16 Vs[64 * 64];
    __shared__ __align__(16) bf16 Ps[4 * 16 * 64];
    __shared__ float padj[64];

    int tid = threadIdx.x, lane = tid & 63, w = tid >> 6;
    int q0 = blockIdx.x * 64, h = blockIdx.y, b = blockIdx.z;
    int ql = qlen[b];

    // stage Q (swizzled source, linear LDS dest)
    {
        const char* qbase =
            (const char*)Q + ((size_t)(b * SS + q0) * HH + h * 64) * 2;
        int lin = tid * 16;
#pragma unroll
        for (int i = 0; i < 2; ++i, lin += 4096) {
            int row = lin >> 7, bir = lin & 127;
            int sbir = bir ^ ((row & 7) << 4);
            gload16((char*)Qs + lin, qbase + (size_t)row * (HH * 2) + sbir);
        }
    }
    int qrow_base = q0 + w * 16 + (lane >> 4) * 4;   // + r
    bool padq[4];
#pragma unroll
    for (int r = 0; r < 4; ++r)
        padq[r] = (ids[b * SS + qrow_base + r] != PAD_ID);

    __syncthreads();
    // Q fragments stay in registers for the whole kernel
    short8 aq[2];
#pragma unroll
    for (int ks = 0; ks < 2; ++ks) {
        int row = w * 16 + (lane & 15);
        int bir = ks * 64 + (lane >> 4) * 16;
        aq[ks] = *(const short8*)((const char*)Qs + row * 128 +
                                  (bir ^ ((row & 7) << 4)));
    }

    float m_run[4], l_run[4];
    f32x4 accO[4];
#pragma unroll
    for (int r = 0; r < 4; ++r) { m_run[r] = -1e30f; l_run[r] = 0.f; }
#pragma unroll
    for (int d = 0; d < 4; ++d) accO[d] = Z4();

    const char* kbase0 = (const char*)K + ((size_t)(b * SS) * HH + h * 64) * 2;
    const char* vbase0 = (const char*)VT + (((size_t)(b * NHH + h)) * 64) * SS * 2;

    for (int kv0 = 0; kv0 < SS; kv0 += 64) {
        __syncthreads();   // previous tile fully consumed
        {
            int lin = tid * 16;
#pragma unroll
            for (int i = 0; i < 2; ++i, lin += 4096) {
                int row = lin >> 7, bir = lin & 127;
                int sbir = bir ^ ((row & 7) << 4);
                gload16((char*)Ks + lin,
                        kbase0 + (size_t)(kv0 + row) * (HH * 2) + sbir);
                gload16((char*)Vs + lin,
                        vbase0 + (size_t)row * (SS * 2) + (size_t)kv0 * 2 + sbir);
            }
        }
        if (tid < 64)
            padj[tid] = (ids[b * SS + kv0 + tid] != PAD_ID) ? 1.f : 0.f;
        __syncthreads();   // staging visible

        // S = Q K^T  (rows=q, cols=kv)
        f32x4 accS[4];
#pragma unroll
        for (int nf = 0; nf < 4; ++nf) {
            f32x4 z = Z4();
#pragma unroll
            for (int ks = 0; ks < 2; ++ks) {
                int row = nf * 16 + (lane & 15);
                int bir = ks * 64 + (lane >> 4) * 16;
                short8 bk = *(const short8*)((const char*)Ks + row * 128 +
                                             (bir ^ ((row & 7) << 4)));
                z = __builtin_amdgcn_mfma_f32_16x16x32_bf16(aq[ks], bk, z, 0, 0, 0);
            }
            accS[nf] = z;
        }

        // mask + scale + online softmax (per q-row = 16-lane groups)
        float p[4][4];        // [r][nf]
#pragma unroll
        for (int r = 0; r < 4; ++r) {
            int qg = qrow_base + r;
            float mx = -1e30f;
#pragma unroll
            for (int nf = 0; nf < 4; ++nf) {
                int j = kv0 + nf * 16 + (lane & 15);
                bool ok = padq[r] && (padj[nf * 16 + (lane & 15)] != 0.f) &&
                          ((qg < ql) || (j < ql) || (j <= qg));
                float s = accS[nf][r] * 0.125f + (ok ? 0.f : -1e9f);
                p[r][nf] = s;
                mx = fmaxf(mx, s);
            }
#pragma unroll
            for (int off = 1; off < 16; off <<= 1)
                mx = fmaxf(mx, __shfl_xor(mx, off));
            float mnew = fmaxf(m_run[r], mx);
            float fac = __expf(m_run[r] - mnew);
            m_run[r] = mnew;
            float rs = 0.f;
#pragma unroll
            for (int nf = 0; nf < 4; ++nf) {
                float e = __expf(p[r][nf] - mnew);
                p[r][nf] = e;
                rs += e;
            }
#pragma unroll
            for (int off = 1; off < 16; off <<= 1)
                rs += __shfl_xor(rs, off);
            l_run[r] = l_run[r] * fac + rs;
#pragma unroll
            for (int df = 0; df < 4; ++df) accO[df][r] *= fac;
        }

        // write P (bf16) to per-wave LDS, swizzled
#pragma unroll
        for (int r = 0; r < 4; ++r) {
            int prow = (lane >> 4) * 4 + r;
#pragma unroll
            for (int nf = 0; nf < 4; ++nf) {
                int c = nf * 16 + (lane & 15);
                int byte = (c * 2) ^ ((prow & 7) << 4);
                *(bf16*)((char*)Ps + w * 2048 + prow * 128 + byte) =
                    __float2bfloat16(p[r][nf]);
            }
        }
        __syncthreads();   // P visible (and K/V reads complete)

        // O += P V  (contraction over kv)
#pragma unroll
        for (int ks = 0; ks < 2; ++ks) {
            int prow = lane & 15;
            int bir = ks * 64 + (lane >> 4) * 16;
            short8 ap = *(const short8*)((const char*)Ps + w * 2048 + prow * 128 +
                                         (bir ^ ((prow & 7) << 4)));
#pragma unroll
            for (int df = 0; df < 4; ++df) {
                int vrow = df * 16 + (lane & 15);
                short8 bv = *(const short8*)((const char*)Vs + vrow * 128 +
                                             (bir ^ ((vrow & 7) << 4)));
                accO[df] = __builtin_amdgcn_mfma_f32_16x16x32_bf16(
                    ap, bv, accO[df], 0, 0, 0);
            }
        }
    }

    // normalize + store
#pragma unroll
    for (int r = 0; r < 4; ++r) {
        int qg = qrow_base + r;
        float inv = 1.0f / l_run[r];
#pragma unroll
        for (int df = 0; df < 4; ++df) {
            int d = df * 16 + (lane & 15);
            att[((size_t)(b * SS) + qg) * HH + h * 64 + d] =
                __float2bfloat16(accO[df][r] * inv);
        }
    }
}

// ---------------------------------------------------------------------------
// launch
// ---------------------------------------------------------------------------
extern "C" void kernel_launch(void* const* d_in, const int* in_sizes, int n_in,
                              void* d_out, int out_size, void* d_ws, size_t ws_size,
                              hipStream_t stream) {
    const int*   ids      = (const int*)d_in[0];
    const float* word_emb = (const float*)d_in[1];
    const float* pos_emb  = (const float*)d_in[2];
    const float* type_emb = (const float*)d_in[3];
    const float* emb_ln_g = (const float*)d_in[4];
    const float* emb_ln_b = (const float*)d_in[5];
    const float* attn_w   = (const float*)d_in[6];
    const float* attn_b   = (const float*)d_in[7];
    const float* ln1_g    = (const float*)d_in[8];
    const float* ln1_b    = (const float*)d_in[9];
    const float* ffn_w1   = (const float*)d_in[10];
    const float* ffn_b1   = (const float*)d_in[11];
    const float* ffn_w2   = (const float*)d_in[12];
    const float* ffn_b2   = (const float*)d_in[13];
    const float* ln2_g    = (const float*)d_in[14];
    const float* ln2_b    = (const float*)d_in[15];
    const float* cls_w    = (const float*)d_in[16];
    const float* cls_b    = (const float*)d_in[17];
    float* out = (float*)d_out;

    // ---- workspace layout (all sizes 256B-multiples) ----
    char* base = (char*)d_ws;
    size_t off = 0;
    auto take = [&](size_t bytes) {
        char* r = base + off;
        off += (bytes + 255) & ~(size_t)255;
        return r;
    };
    float* h    = (float*)take(BSH * 4);
    float* proj = (float*)take(BSH * 4);      // start of 69MB reusable span
    bf16*  qb   = (bf16*)take(BSH * 2);
    bf16*  kb   = (bf16*)take(BSH * 2);
    bf16*  vb   = (bf16*)take(BSH * 2);
    bf16*  vT   = (bf16*)take(BSH * 2);
    bf16*  attb = (bf16*)take(BSH * 2);
    bf16*  ffb  = (bf16*)take(BSFF * 2);      // end of reusable span
    bf16*  hb   = (bf16*)take(BSH * 2);
    int*   qlen = (int*)take(256);
    size_t commonEnd = off;

    const size_t szAttnW = (size_t)48 * HH * HH * 2;
    const size_t szW1    = (size_t)LL * HH * FFF * 2;
    const size_t szCls   = (size_t)VV * HH * 2;
    const size_t fullNeed = commonEnd + szAttnW + 2 * szW1 + szCls;
    bool fullMode = (ws_size >= fullNeed);

    bf16 *wAttnT = nullptr, *w1T = nullptr, *w2T = nullptr, *clsT = nullptr, *wrot = nullptr;
    if (fullMode) {
        wAttnT = (bf16*)take(szAttnW);
        w1T    = (bf16*)take(szW1);
        w2T    = (bf16*)take(szW1);
        clsT   = (bf16*)take(szCls);
    } else {
        wrot = (bf16*)take((size_t)HH * FFF * 2);   // per-layer rotating buffer
        clsT = (bf16*)proj;                          // cls weight -> dead span
    }

    auto convw = [&](const float* src, bf16* dst, int K, int N) {
        dim3 g((N + 63) / 64, (K + 63) / 64, 1);
        transp_conv<<<g, 256, 0, stream>>>(src, dst, K, N, (size_t)0, (size_t)0);
    };

    qlen_kernel<<<BB, 256, 0, stream>>>(ids, qlen);

    if (fullMode) {
        transp_conv<<<dim3(12, 12, 48), 256, 0, stream>>>(
            attn_w, wAttnT, HH, HH, (size_t)HH * HH, (size_t)HH * HH);
        transp_conv<<<dim3(FFF / 64, HH / 64, LL), 256, 0, stream>>>(
            ffn_w1, w1T, HH, FFF, (size_t)HH * FFF, (size_t)HH * FFF);
        transp_conv<<<dim3(HH / 64, FFF / 64, LL), 256, 0, stream>>>(
            ffn_w2, w2T, FFF, HH, (size_t)HH * FFF, (size_t)HH * FFF);
        transp_conv<<<dim3((VV + 63) / 64, HH / 64, 1), 256, 0, stream>>>(
            cls_w, clsT, HH, VV, (size_t)0, (size_t)0);
    }

    embed_ln_kernel<<<BS, 256, 0, stream>>>(ids, word_emb, pos_emb, type_emb,
                                            emb_ln_g, emb_ln_b, h, hb);

    dim3 gProj(HH / GBN, BS / GBM);          // 6 x 32
    dim3 gFF1(FFF / GBN, BS / GBM);          // 24 x 32
    dim3 gCls((VV + GBN - 1) / GBN, BS / GBM);  // 166 x 32
    dim3 gAttn(SS / 64, NHH, BB);
    dim3 gVT(SS / 64, NHH, BB);

    for (int l = 0; l < LL; ++l) {
        const float* wq32 = attn_w + (size_t)l * 4 * HH * HH;
        const float* wk32 = wq32 + (size_t)HH * HH;
        const float* wv32 = wk32 + (size_t)HH * HH;
        const float* wo32 = wv32 + (size_t)HH * HH;
        const float* bq = attn_b + (size_t)l * 4 * HH;
        const float* bk = bq + HH;
        const float* bv = bk + HH;
        const float* bo = bv + HH;

        bf16 *wqT, *wkT, *wvT, *woT, *w1Tl, *w2Tl;
        if (fullMode) {
            wqT = wAttnT + (size_t)(l * 4 + 0) * HH * HH;
            wkT = wAttnT + (size_t)(l * 4 + 1) * HH * HH;
            wvT = wAttnT + (size_t)(l * 4 + 2) * HH * HH;
            woT = wAttnT + (size_t)(l * 4 + 3) * HH * HH;
            w1Tl = w1T + (size_t)l * HH * FFF;
            w2Tl = w2T + (size_t)l * HH * FFF;
        } else {
            wqT = wkT = wvT = woT = w1Tl = w2Tl = wrot;
        }

        if (!fullMode) convw(wq32, wrot, HH, HH);
        gemm_bf16_kernel<1, 0><<<gProj, 256, 0, stream>>>(hb, wqT, bq, qb, BS, HH, HH);
        if (!fullMode) convw(wk32, wrot, HH, HH);
        gemm_bf16_kernel<1, 0><<<gProj, 256, 0, stream>>>(hb, wkT, bk, kb, BS, HH, HH);
        if (!fullMode) convw(wv32, wrot, HH, HH);
        gemm_bf16_kernel<1, 0><<<gProj, 256, 0, stream>>>(hb, wvT, bv, vb, BS, HH, HH);

        vtrans_kernel<<<gVT, 256, 0, stream>>>(vb, vT);
        attn_mfma_kernel<<<gAttn, 256, 0, stream>>>(qb, kb, vT, ids, qlen, attb);

        if (!fullMode) convw(wo32, wrot, HH, HH);
        gemm_bf16_kernel<0, 0><<<gProj, 256, 0, stream>>>(attb, woT, bo, proj, BS, HH, HH);
        add_ln_kernel<<<BS, 256, 0, stream>>>(h, proj, ln1_g + (size_t)l * HH,
                                              ln1_b + (size_t)l * HH, hb);

        if (!fullMode) convw(ffn_w1 + (size_t)l * HH * FFF, wrot, HH, FFF);
        gemm_bf16_kernel<1, 1><<<gFF1, 256, 0, stream>>>(
            hb, w1Tl, ffn_b1 + (size_t)l * FFF, ffb, BS, FFF, HH);
        if (!fullMode) convw(ffn_w2 + (size_t)l * HH * FFF, wrot, FFF, HH);
        gemm_bf16_kernel<0, 0><<<gProj, 256, 0, stream>>>(
            ffb, w2Tl, ffn_b2 + (size_t)l * HH, proj, BS, HH, FFF);
        add_ln_kernel<<<BS, 256, 0, stream>>>(h, proj, ln2_g + (size_t)l * HH,
                                              ln2_b + (size_t)l * HH, hb);
    }

    if (!fullMode) convw(cls_w, clsT, HH, VV);
    gemm_bf16_kernel<0, 0><<<gCls, 256, 0, stream>>>(hb, clsT, cls_b, out, BS, VV, HH);
}

// Round 3
// 3159.502 us; speedup vs baseline: 12.8318x; 1.3503x over previous
//
#include <hip/hip_runtime.h>
#include <hip/hip_bf16.h>
#include <stdint.h>

// ---- problem constants ----
#define BB   8
#define SS   512
#define HH   768
#define LL   12
#define NHH  12
#define DHH  64
#define FFF  3072
#define VV   21128
#define PAD_ID 0
#define SEP_ID 102
#define BS   (BB*SS)              // 4096
#define BSH  ((size_t)BS*HH)      // 3,145,728
#define BSFF ((size_t)BS*FFF)     // 12,582,912
#define QKVN (3*HH)               // 2304

using bf16 = __hip_bfloat16;
typedef __attribute__((ext_vector_type(8))) short short8;
typedef __attribute__((ext_vector_type(4))) float f32x4;

__device__ __forceinline__ f32x4 Z4() { f32x4 z = {0.f, 0.f, 0.f, 0.f}; return z; }

// async global->LDS, 16B per lane. LDS dest must be wave-uniform base + lane*16.
__device__ __forceinline__ void gload16(void* lds, const void* g) {
    __builtin_amdgcn_global_load_lds(
        (const __attribute__((address_space(1))) uint32_t*)g,
        (__attribute__((address_space(3))) uint32_t*)(uint32_t)(uintptr_t)lds,
        16, 0, 0);
}

// ---------------------------------------------------------------------------
// qlen[b] = (first j with ids[b,j]==SEP else 0) + 1
// ---------------------------------------------------------------------------
__global__ void __launch_bounds__(256) qlen_kernel(const int* __restrict__ ids,
                                                   int* __restrict__ qlen) {
    int b = blockIdx.x, tid = threadIdx.x;
    __shared__ int red[256];
    int best = 1 << 30;
    for (int j = tid; j < SS; j += 256)
        if (ids[b * SS + j] == SEP_ID) best = min(best, j);
    red[tid] = best; __syncthreads();
    for (int off = 128; off > 0; off >>= 1) {
        if (tid < off) red[tid] = min(red[tid], red[tid + off]);
        __syncthreads();
    }
    if (tid == 0) qlen[b] = (red[0] == (1 << 30) ? 0 : red[0]) + 1;
}

// ---------------------------------------------------------------------------
// block reduce (256 thr)
// ---------------------------------------------------------------------------
__device__ __forceinline__ float block_reduce_sum(float v, float* red, int tid) {
    red[tid] = v; __syncthreads();
    for (int off = 128; off > 0; off >>= 1) {
        if (tid < off) red[tid] += red[tid + off];
        __syncthreads();
    }
    float r = red[0]; __syncthreads();
    return r;
}

// ---------------------------------------------------------------------------
// embedding gather + LN  -> h (f32) and hb (bf16)
// ---------------------------------------------------------------------------
__global__ void __launch_bounds__(256) embed_ln_kernel(
    const int* __restrict__ ids, const float* __restrict__ we,
    const float* __restrict__ pe, const float* __restrict__ te,
    const float* __restrict__ g, const float* __restrict__ bt,
    float* __restrict__ h, bf16* __restrict__ hb) {
    int token = blockIdx.x, tid = threadIdx.x;
    int s = token % SS;
    int id = ids[token];
    __shared__ float red[256];
    float x[3];
#pragma unroll
    for (int i = 0; i < 3; ++i) {
        int idx = tid + i * 256;
        x[i] = we[(size_t)id * HH + idx] + pe[(size_t)s * HH + idx] + te[idx];
    }
    float sum = block_reduce_sum(x[0] + x[1] + x[2], red, tid);
    float mu = sum * (1.0f / HH);
    float vs = 0.f;
#pragma unroll
    for (int i = 0; i < 3; ++i) { float d = x[i] - mu; vs += d * d; }
    vs = block_reduce_sum(vs, red, tid);
    float rstd = rsqrtf(vs * (1.0f / HH) + 1e-12f);
    size_t base = (size_t)token * HH;
#pragma unroll
    for (int i = 0; i < 3; ++i) {
        int idx = tid + i * 256;
        float v = (x[i] - mu) * rstd * g[idx] + bt[idx];
        h[base + idx] = v;
        hb[base + idx] = __float2bfloat16(v);
    }
}

// ---------------------------------------------------------------------------
// h = LN(h + proj)  -> h (f32) and hb (bf16)
// ---------------------------------------------------------------------------
__global__ void __launch_bounds__(256) add_ln_kernel(
    float* __restrict__ h, const float* __restrict__ proj,
    const float* __restrict__ g, const float* __restrict__ bt,
    bf16* __restrict__ hb) {
    int token = blockIdx.x, tid = threadIdx.x;
    __shared__ float red[256];
    size_t base = (size_t)token * HH;
    float x[3];
#pragma unroll
    for (int i = 0; i < 3; ++i) {
        int idx = tid + i * 256;
        x[i] = h[base + idx] + proj[base + idx];
    }
    float sum = block_reduce_sum(x[0] + x[1] + x[2], red, tid);
    float mu = sum * (1.0f / HH);
    float vs = 0.f;
#pragma unroll
    for (int i = 0; i < 3; ++i) { float d = x[i] - mu; vs += d * d; }
    vs = block_reduce_sum(vs, red, tid);
    float rstd = rsqrtf(vs * (1.0f / HH) + 1e-12f);
#pragma unroll
    for (int i = 0; i < 3; ++i) {
        int idx = tid + i * 256;
        float v = (x[i] - mu) * rstd * g[idx] + bt[idx];
        h[base + idx] = v;
        hb[base + idx] = __float2bfloat16(v);
    }
}

// ---------------------------------------------------------------------------
// transpose-convert: in f32 [K][N] (row-major) -> out bf16 [N][K]
// ---------------------------------------------------------------------------
__global__ void __launch_bounds__(256) transp_conv(
    const float* __restrict__ in, bf16* __restrict__ out,
    int K, int N, size_t inStride, size_t outStride) {
    const float* src = in + (size_t)blockIdx.z * inStride;
    bf16* dst = out + (size_t)blockIdx.z * outStride;
    __shared__ float t[64][65];
    int n0 = blockIdx.x * 64, k0 = blockIdx.y * 64;
    int tid = threadIdx.x;
#pragma unroll
    for (int i = 0; i < 16; ++i) {
        int lin = tid + i * 256;
        int r = lin >> 6, c = lin & 63;
        int kk = k0 + r, nn = n0 + c;
        t[r][c] = (kk < K && nn < N) ? src[(size_t)kk * N + nn] : 0.f;
    }
    __syncthreads();
#pragma unroll
    for (int i = 0; i < 16; ++i) {
        int lin = tid + i * 256;
        int r = lin >> 6, c = lin & 63;
        int nn = n0 + r, kk = k0 + c;
        if (nn < N && kk < K)
            dst[(size_t)nn * K + kk] = __float2bfloat16(t[c][r]);
    }
}

// ---------------------------------------------------------------------------
// v slice of qkv [BS][ldv] bf16 -> vT [B][NH][DH][S] bf16
// ---------------------------------------------------------------------------
__global__ void __launch_bounds__(256) vtrans_kernel(const bf16* __restrict__ v,
                                                     bf16* __restrict__ vT,
                                                     int ldv) {
    __shared__ bf16 t[64][66];
    int s0 = blockIdx.x * 64, h = blockIdx.y, b = blockIdx.z;
    int tid = threadIdx.x;
#pragma unroll
    for (int i = 0; i < 16; ++i) {
        int lin = tid + i * 256;
        int sr = lin >> 6, dc = lin & 63;
        t[sr][dc] = v[((size_t)(b * SS + s0 + sr)) * ldv + h * 64 + dc];
    }
    __syncthreads();
#pragma unroll
    for (int i = 0; i < 16; ++i) {
        int lin = tid + i * 256;
        int dr = lin >> 6, sc = lin & 63;
        vT[(((size_t)(b * NHH + h)) * 64 + dr) * SS + s0 + sc] = t[sc][dr];
    }
}

// ---------------------------------------------------------------------------
// bf16 MFMA GEMM: C[M,N](ldc) = A[M,K] @ BT[N,K]^T + bias
// TBMxTBN tile, BK=32, 4 waves, 16x16x32 MFMA, global_load_lds staging.
// LDS rows (64B = 32 bf16 of K) are slot-swizzled: slot ^= row&3 (T2, rule 21:
// swizzle applied to global SOURCE col + fragment READ, LDS dest stays linear).
// XCD-chunked block swizzle (T1) when nwg%8==0.
// ---------------------------------------------------------------------------
#define GBK 32

template <int TBM, int TBN, int OUT_BF16, int ACT>
__global__ void __launch_bounds__(256) gemm_bf16_kernel(
    const bf16* __restrict__ A, const bf16* __restrict__ BT,
    const float* __restrict__ bias, void* __restrict__ Cout,
    int M, int N, int K, int ldc) {
    constexpr int MFRAG = TBM / 32;   // frags per wave (wave tile TBM/2)
    constexpr int NFRAG = TBN / 32;
    __shared__ __align__(16) bf16 As[TBM * GBK];
    __shared__ __align__(16) bf16 Bs[TBN * GBK];
    int tid = threadIdx.x;
    int lane = tid & 63, wid = tid >> 6;

    // T1: XCD-chunked swizzle (bijective when nwg%8==0)
    int nwg = gridDim.x * gridDim.y;
    int bid = blockIdx.y * gridDim.x + blockIdx.x;
    int swz = ((nwg & 7) == 0) ? ((bid & 7) * (nwg >> 3) + (bid >> 3)) : bid;
    int bx = swz % gridDim.x, by = swz / gridDim.x;

    int m0 = by * TBM, n0 = bx * TBN;
    int wr = (wid >> 1) * (TBM / 2), wc = (wid & 1) * (TBN / 2);

    f32x4 acc[MFRAG][NFRAG];
#pragma unroll
    for (int i = 0; i < MFRAG; ++i)
#pragma unroll
        for (int j = 0; j < NFRAG; ++j) acc[i][j] = Z4();

    const char* Ab = (const char*)A;
    const char* Bb = (const char*)BT;

    for (int k0 = 0; k0 < K; k0 += GBK) {
#pragma unroll
        for (int i = 0; i < TBM / 64; ++i) {
            int lin = tid * 16 + i * 4096;
            int row = lin >> 6, slot = (lin >> 4) & 3;
            gload16((char*)As + lin,
                    Ab + ((size_t)(m0 + row) * K + k0) * 2 +
                        ((slot ^ (row & 3)) << 4));
        }
#pragma unroll
        for (int i = 0; i < TBN / 64; ++i) {
            int lin = tid * 16 + i * 4096;
            int row = lin >> 6, slot = (lin >> 4) & 3;
            int nr = n0 + row; if (nr >= N) nr = N - 1;
            gload16((char*)Bs + lin,
                    Bb + ((size_t)nr * K + k0) * 2 +
                        ((slot ^ (row & 3)) << 4));
        }
        __syncthreads();   // drains vmcnt -> staged data visible

        short8 af[MFRAG], bfr[NFRAG];
#pragma unroll
        for (int i = 0; i < MFRAG; ++i) {
            int ar = wr + i * 16 + (lane & 15);
            int slot = (lane >> 4) ^ (ar & 3);
            af[i] = *(const short8*)((const char*)As + ar * 64 + slot * 16);
        }
#pragma unroll
        for (int j = 0; j < NFRAG; ++j) {
            int br = wc + j * 16 + (lane & 15);
            int slot = (lane >> 4) ^ (br & 3);
            bfr[j] = *(const short8*)((const char*)Bs + br * 64 + slot * 16);
        }
#pragma unroll
        for (int i = 0; i < MFRAG; ++i)
#pragma unroll
            for (int j = 0; j < NFRAG; ++j)
                acc[i][j] = __builtin_amdgcn_mfma_f32_16x16x32_bf16(
                    af[i], bfr[j], acc[i][j], 0, 0, 0);
        __syncthreads();
    }

    bool nfull = (n0 + TBN <= N);
#pragma unroll
    for (int i = 0; i < MFRAG; ++i) {
#pragma unroll
        for (int r = 0; r < 4; ++r) {
            int m = m0 + wr + i * 16 + (lane >> 4) * 4 + r;
#pragma unroll
            for (int j = 0; j < NFRAG; ++j) {
                int n = n0 + wc + j * 16 + (lane & 15);
                if (nfull || n < N) {
                    float v = acc[i][j][r] + bias[n];
                    if (ACT) v = 0.5f * v * (1.0f + erff(v * 0.70710678118654752f));
                    if (OUT_BF16)
                        ((bf16*)Cout)[(size_t)m * ldc + n] = __float2bfloat16(v);
                    else
                        ((float*)Cout)[(size_t)m * ldc + n] = v;
                }
            }
        }
    }
}

// ---------------------------------------------------------------------------
// flash attention, bf16 MFMA. Block = 64 q-rows (4 waves x 16), KV tiles of 64.
// Q,K: head slices of qkv [BS][ld] bf16; VT: [B][NH][DH][S] bf16.
// att out: [BS][H] bf16. LDS XOR-swizzled: byte ^= (row&7)<<4 (128B rows).
// ---------------------------------------------------------------------------
__global__ void __launch_bounds__(256) attn_mfma_kernel(
    const bf16* __restrict__ Q, const bf16* __restrict__ K,
    const bf16* __restrict__ VT, const int* __restrict__ ids,
    const int* __restrict__ qlen, bf16* __restrict__ att, int ld) {
    __shared__ __align__(16) bf16 Qs[64 * 64];
    __shared__ __align__(16) bf16 Ks[64 * 64];
    __shared__ __align__(16) bf16 Vs[64 * 64];
    __shared__ __align__(16) bf16 Ps[4 * 16 * 64];
    __shared__ float padj[64];

    int tid = threadIdx.x, lane = tid & 63, w = tid >> 6;
    int q0 = blockIdx.x * 64, h = blockIdx.y, b = blockIdx.z;
    int ql = qlen[b];

    // stage Q (swizzled source, linear LDS dest)
    {
        const char* qbase =
            (const char*)Q + ((size_t)(b * SS + q0) * ld + h * 64) * 2;
        int lin = tid * 16;
#pragma unroll
        for (int i = 0; i < 2; ++i, lin += 4096) {
            int row = lin >> 7, bir = lin & 127;
            int sbir = bir ^ ((row & 7) << 4);
            gload16((char*)Qs + lin, qbase + (size_t)row * (ld * 2) + sbir);
        }
    }
    int qrow_base = q0 + w * 16 + (lane >> 4) * 4;   // + r
    bool padq[4];
#pragma unroll
    for (int r = 0; r < 4; ++r)
        padq[r] = (ids[b * SS + qrow_base + r] != PAD_ID);

    __syncthreads();
    // Q fragments stay in registers for the whole kernel
    short8 aq[2];
#pragma unroll
    for (int ks = 0; ks < 2; ++ks) {
        int row = w * 16 + (lane & 15);
        int bir = ks * 64 + (lane >> 4) * 16;
        aq[ks] = *(const short8*)((const char*)Qs + row * 128 +
                                  (bir ^ ((row & 7) << 4)));
    }

    float m_run[4], l_run[4];
    f32x4 accO[4];
#pragma unroll
    for (int r = 0; r < 4; ++r) { m_run[r] = -1e30f; l_run[r] = 0.f; }
#pragma unroll
    for (int d = 0; d < 4; ++d) accO[d] = Z4();

    const char* kbase0 = (const char*)K + ((size_t)(b * SS) * ld) * 2;
    const char* vbase0 = (const char*)VT + (((size_t)(b * NHH + h)) * 64) * SS * 2;

    for (int kv0 = 0; kv0 < SS; kv0 += 64) {
        __syncthreads();   // previous tile fully consumed
        {
            int lin = tid * 16;
#pragma unroll
            for (int i = 0; i < 2; ++i, lin += 4096) {
                int row = lin >> 7, bir = lin & 127;
                int sbir = bir ^ ((row & 7) << 4);
                gload16((char*)Ks + lin,
                        kbase0 + (size_t)(kv0 + row) * (ld * 2) + h * 128 + sbir);
                gload16((char*)Vs + lin,
                        vbase0 + (size_t)row * (SS * 2) + (size_t)kv0 * 2 + sbir);
            }
        }
        if (tid < 64)
            padj[tid] = (ids[b * SS + kv0 + tid] != PAD_ID) ? 1.f : 0.f;
        __syncthreads();   // staging visible

        // S = Q K^T  (rows=q, cols=kv)
        f32x4 accS[4];
        __builtin_amdgcn_s_setprio(1);
#pragma unroll
        for (int nf = 0; nf < 4; ++nf) {
            f32x4 z = Z4();
#pragma unroll
            for (int ks = 0; ks < 2; ++ks) {
                int row = nf * 16 + (lane & 15);
                int bir = ks * 64 + (lane >> 4) * 16;
                short8 bk = *(const short8*)((const char*)Ks + row * 128 +
                                             (bir ^ ((row & 7) << 4)));
                z = __builtin_amdgcn_mfma_f32_16x16x32_bf16(aq[ks], bk, z, 0, 0, 0);
            }
            accS[nf] = z;
        }
        __builtin_amdgcn_s_setprio(0);

        // mask + scale + online softmax (per q-row = 16-lane groups)
        float p[4][4];        // [r][nf]
#pragma unroll
        for (int r = 0; r < 4; ++r) {
            int qg = qrow_base + r;
            float mx = -1e30f;
#pragma unroll
            for (int nf = 0; nf < 4; ++nf) {
                int j = kv0 + nf * 16 + (lane & 15);
                bool ok = padq[r] && (padj[nf * 16 + (lane & 15)] != 0.f) &&
                          ((qg < ql) || (j < ql) || (j <= qg));
                float s = accS[nf][r] * 0.125f + (ok ? 0.f : -1e9f);
                p[r][nf] = s;
                mx = fmaxf(mx, s);
            }
#pragma unroll
            for (int off = 1; off < 16; off <<= 1)
                mx = fmaxf(mx, __shfl_xor(mx, off));
            float mnew = fmaxf(m_run[r], mx);
            float fac = __expf(m_run[r] - mnew);
            m_run[r] = mnew;
            float rs = 0.f;
#pragma unroll
            for (int nf = 0; nf < 4; ++nf) {
                float e = __expf(p[r][nf] - mnew);
                p[r][nf] = e;
                rs += e;
            }
#pragma unroll
            for (int off = 1; off < 16; off <<= 1)
                rs += __shfl_xor(rs, off);
            l_run[r] = l_run[r] * fac + rs;
#pragma unroll
            for (int df = 0; df < 4; ++df) accO[df][r] *= fac;
        }

        // write P (bf16) to per-wave LDS, swizzled
#pragma unroll
        for (int r = 0; r < 4; ++r) {
            int prow = (lane >> 4) * 4 + r;
#pragma unroll
            for (int nf = 0; nf < 4; ++nf) {
                int c = nf * 16 + (lane & 15);
                int byte = (c * 2) ^ ((prow & 7) << 4);
                *(bf16*)((char*)Ps + w * 2048 + prow * 128 + byte) =
                    __float2bfloat16(p[r][nf]);
            }
        }
        __syncthreads();   // P visible (and K/V reads complete)

        // O += P V  (contraction over kv)
        __builtin_amdgcn_s_setprio(1);
#pragma unroll
        for (int ks = 0; ks < 2; ++ks) {
            int prow = lane & 15;
            int bir = ks * 64 + (lane >> 4) * 16;
            short8 ap = *(const short8*)((const char*)Ps + w * 2048 + prow * 128 +
                                         (bir ^ ((prow & 7) << 4)));
#pragma unroll
            for (int df = 0; df < 4; ++df) {
                int vrow = df * 16 + (lane & 15);
                short8 bv = *(const short8*)((const char*)Vs + vrow * 128 +
                                             (bir ^ ((vrow & 7) << 4)));
                accO[df] = __builtin_amdgcn_mfma_f32_16x16x32_bf16(
                    ap, bv, accO[df], 0, 0, 0);
            }
        }
        __builtin_amdgcn_s_setprio(0);
    }

    // normalize + store
#pragma unroll
    for (int r = 0; r < 4; ++r) {
        int qg = qrow_base + r;
        float inv = 1.0f / l_run[r];
#pragma unroll
        for (int df = 0; df < 4; ++df) {
            int d = df * 16 + (lane & 15);
            att[((size_t)(b * SS) + qg) * HH + h * 64 + d] =
                __float2bfloat16(accO[df][r] * inv);
        }
    }
}

// ---------------------------------------------------------------------------
// launch
// ---------------------------------------------------------------------------
extern "C" void kernel_launch(void* const* d_in, const int* in_sizes, int n_in,
                              void* d_out, int out_size, void* d_ws, size_t ws_size,
                              hipStream_t stream) {
    const int*   ids      = (const int*)d_in[0];
    const float* word_emb = (const float*)d_in[1];
    const float* pos_emb  = (const float*)d_in[2];
    const float* type_emb = (const float*)d_in[3];
    const float* emb_ln_g = (const float*)d_in[4];
    const float* emb_ln_b = (const float*)d_in[5];
    const float* attn_w   = (const float*)d_in[6];
    const float* attn_b   = (const float*)d_in[7];
    const float* ln1_g    = (const float*)d_in[8];
    const float* ln1_b    = (const float*)d_in[9];
    const float* ffn_w1   = (const float*)d_in[10];
    const float* ffn_b1   = (const float*)d_in[11];
    const float* ffn_w2   = (const float*)d_in[12];
    const float* ffn_b2   = (const float*)d_in[13];
    const float* ln2_g    = (const float*)d_in[14];
    const float* ln2_b    = (const float*)d_in[15];
    const float* cls_w    = (const float*)d_in[16];
    const float* cls_b    = (const float*)d_in[17];
    float* out = (float*)d_out;

    // ---- workspace layout ----
    char* base = (char*)d_ws;
    size_t off = 0;
    auto take = [&](size_t bytes) {
        char* r = base + off;
        off += (bytes + 255) & ~(size_t)255;
        return r;
    };
    float* h    = (float*)take(BSH * 4);
    float* proj = (float*)take(BSH * 4);          // start of reusable span
    bf16*  qkv  = (bf16*)take((size_t)BS * QKVN * 2);  // [BS][2304]
    bf16*  vT   = (bf16*)take(BSH * 2);
    bf16*  attb = (bf16*)take(BSH * 2);
    bf16*  ffb  = (bf16*)take(BSFF * 2);          // end of reusable span
    bf16*  hb   = (bf16*)take(BSH * 2);
    int*   qlen = (int*)take(256);
    size_t commonEnd = off;

    const size_t szAttnW = (size_t)48 * HH * HH * 2;
    const size_t szW1    = (size_t)LL * HH * FFF * 2;
    const size_t szCls   = (size_t)VV * HH * 2;
    const size_t fullNeed = commonEnd + szAttnW + 2 * szW1 + szCls;
    bool fullMode = (ws_size >= fullNeed);

    bf16 *wAttnT = nullptr, *w1T = nullptr, *w2T = nullptr, *clsT = nullptr, *wrot = nullptr;
    if (fullMode) {
        wAttnT = (bf16*)take(szAttnW);
        w1T    = (bf16*)take(szW1);
        w2T    = (bf16*)take(szW1);
        clsT   = (bf16*)take(szCls);
    } else {
        wrot = (bf16*)take((size_t)HH * FFF * 2);   // rotating buffer
        clsT = (bf16*)proj;                          // cls weight -> dead span
    }

    auto convw = [&](const float* src, bf16* dst, int K, int N) {
        dim3 g((N + 63) / 64, (K + 63) / 64, 1);
        transp_conv<<<g, 256, 0, stream>>>(src, dst, K, N, (size_t)0, (size_t)0);
    };

    qlen_kernel<<<BB, 256, 0, stream>>>(ids, qlen);

    if (fullMode) {
        transp_conv<<<dim3(12, 12, 48), 256, 0, stream>>>(
            attn_w, wAttnT, HH, HH, (size_t)HH * HH, (size_t)HH * HH);
        transp_conv<<<dim3(FFF / 64, HH / 64, LL), 256, 0, stream>>>(
            ffn_w1, w1T, HH, FFF, (size_t)HH * FFF, (size_t)HH * FFF);
        transp_conv<<<dim3(HH / 64, FFF / 64, LL), 256, 0, stream>>>(
            ffn_w2, w2T, FFF, HH, (size_t)HH * FFF, (size_t)HH * FFF);
        transp_conv<<<dim3((VV + 63) / 64, HH / 64, 1), 256, 0, stream>>>(
            cls_w, clsT, HH, VV, (size_t)0, (size_t)0);
    }

    embed_ln_kernel<<<BS, 256, 0, stream>>>(ids, word_emb, pos_emb, type_emb,
                                            emb_ln_g, emb_ln_b, h, hb);

    dim3 gQKV(QKVN / 128, BS / 128);             // 18 x 32 = 576
    dim3 gWo(HH / 64, BS / 128);                 // 12 x 32 = 384 (128x64 tile)
    dim3 gFF1(FFF / 128, BS / 128);              // 24 x 32 = 768
    dim3 gFF2(HH / 64, BS / 128);                // 12 x 32 = 384 (128x64 tile)
    dim3 gCls((VV + 127) / 128, BS / 128);       // 166 x 32 = 5312
    dim3 gAttn(SS / 64, NHH, BB);
    dim3 gVT(SS / 64, NHH, BB);

    for (int l = 0; l < LL; ++l) {
        const float* wq32 = attn_w + (size_t)l * 4 * HH * HH;
        const float* wo32 = wq32 + (size_t)3 * HH * HH;
        const float* bqkv = attn_b + (size_t)l * 4 * HH;   // q,k,v contiguous
        const float* bo   = bqkv + 3 * HH;

        bf16 *wqkvT, *woT, *w1Tl, *w2Tl;
        if (fullMode) {
            wqkvT = wAttnT + (size_t)(l * 4) * HH * HH;    // [2304][768]
            woT   = wAttnT + (size_t)(l * 4 + 3) * HH * HH;
            w1Tl  = w1T + (size_t)l * HH * FFF;
            w2Tl  = w2T + (size_t)l * HH * FFF;
        } else {
            wqkvT = woT = w1Tl = w2Tl = wrot;
        }

        if (!fullMode) {
            convw(wq32, wrot, HH, HH);
            convw(wq32 + (size_t)HH * HH, wrot + (size_t)HH * HH, HH, HH);
            convw(wq32 + (size_t)2 * HH * HH, wrot + (size_t)2 * HH * HH, HH, HH);
        }
        gemm_bf16_kernel<128, 128, 1, 0><<<gQKV, 256, 0, stream>>>(
            hb, wqkvT, bqkv, qkv, BS, QKVN, HH, QKVN);

        vtrans_kernel<<<gVT, 256, 0, stream>>>(qkv + 2 * HH, vT, QKVN);
        attn_mfma_kernel<<<gAttn, 256, 0, stream>>>(
            qkv, qkv + HH, vT, ids, qlen, attb, QKVN);

        if (!fullMode) convw(wo32, wrot, HH, HH);
        gemm_bf16_kernel<128, 64, 0, 0><<<gWo, 256, 0, stream>>>(
            attb, woT, bo, proj, BS, HH, HH, HH);
        add_ln_kernel<<<BS, 256, 0, stream>>>(h, proj, ln1_g + (size_t)l * HH,
                                              ln1_b + (size_t)l * HH, hb);

        if (!fullMode) convw(ffn_w1 + (size_t)l * HH * FFF, wrot, HH, FFF);
        gemm_bf16_kernel<128, 128, 1, 1><<<gFF1, 256, 0, stream>>>(
            hb, w1Tl, ffn_b1 + (size_t)l * FFF, ffb, BS, FFF, HH, FFF);
        if (!fullMode) convw(ffn_w2 + (size_t)l * HH * FFF, wrot, FFF, HH);
        gemm_bf16_kernel<128, 64, 0, 0><<<gFF2, 256, 0, stream>>>(
            ffb, w2Tl, ffn_b2 + (size_t)l * HH, proj, BS, HH, FFF, HH);
        add_ln_kernel<<<BS, 256, 0, stream>>>(h, proj, ln2_g + (size_t)l * HH,
                                              ln2_b + (size_t)l * HH, hb);
    }

    if (!fullMode) convw(cls_w, clsT, HH, VV);
    gemm_bf16_kernel<128, 128, 0, 0><<<gCls, 256, 0, stream>>>(
        hb, clsT, cls_b, out, BS, VV, HH, VV);
}

// Round 4
// 2787.288 us; speedup vs baseline: 14.5454x; 1.1335x over previous
//
#include <hip/hip_runtime.h>
#include <hip/hip_bf16.h>
#include <stdint.h>

// ---- problem constants ----
#define BB   8
#define SS   512
#define HH   768
#define LL   12
#define NHH  12
#define DHH  64
#define FFF  3072
#define VV   21128
#define PAD_ID 0
#define SEP_ID 102
#define BS   (BB*SS)              // 4096
#define BSH  ((size_t)BS*HH)      // 3,145,728
#define BSFF ((size_t)BS*FFF)     // 12,582,912
#define QKVN (3*HH)               // 2304

using bf16 = __hip_bfloat16;
typedef __attribute__((ext_vector_type(8))) short short8;
typedef __attribute__((ext_vector_type(4))) float f32x4;

__device__ __forceinline__ f32x4 Z4() { f32x4 z = {0.f, 0.f, 0.f, 0.f}; return z; }

// async global->LDS, 16B per lane. LDS dest must be wave-uniform base + lane*16.
__device__ __forceinline__ void gload16(void* lds, const void* g) {
    __builtin_amdgcn_global_load_lds(
        (const __attribute__((address_space(1))) uint32_t*)g,
        (__attribute__((address_space(3))) uint32_t*)(uint32_t)(uintptr_t)lds,
        16, 0, 0);
}

__device__ __forceinline__ void wait_vm0_barrier() {
    asm volatile("s_waitcnt vmcnt(0)" ::: "memory");
    __builtin_amdgcn_sched_barrier(0);
    __builtin_amdgcn_s_barrier();
    __builtin_amdgcn_sched_barrier(0);
}

__device__ __forceinline__ void wait_vm0_lgkm0_barrier() {
    asm volatile("s_waitcnt vmcnt(0) lgkmcnt(0)" ::: "memory");
    __builtin_amdgcn_sched_barrier(0);
    __builtin_amdgcn_s_barrier();
    __builtin_amdgcn_sched_barrier(0);
}

// ---------------------------------------------------------------------------
// qlen[b] = (first j with ids[b,j]==SEP else 0) + 1
// ---------------------------------------------------------------------------
__global__ void __launch_bounds__(256) qlen_kernel(const int* __restrict__ ids,
                                                   int* __restrict__ qlen) {
    int b = blockIdx.x, tid = threadIdx.x;
    __shared__ int red[256];
    int best = 1 << 30;
    for (int j = tid; j < SS; j += 256)
        if (ids[b * SS + j] == SEP_ID) best = min(best, j);
    red[tid] = best; __syncthreads();
    for (int off = 128; off > 0; off >>= 1) {
        if (tid < off) red[tid] = min(red[tid], red[tid + off]);
        __syncthreads();
    }
    if (tid == 0) qlen[b] = (red[0] == (1 << 30) ? 0 : red[0]) + 1;
}

// ---------------------------------------------------------------------------
// block reduce (256 thr)
// ---------------------------------------------------------------------------
__device__ __forceinline__ float block_reduce_sum(float v, float* red, int tid) {
    red[tid] = v; __syncthreads();
    for (int off = 128; off > 0; off >>= 1) {
        if (tid < off) red[tid] += red[tid + off];
        __syncthreads();
    }
    float r = red[0]; __syncthreads();
    return r;
}

// ---------------------------------------------------------------------------
// embedding gather + LN  -> h (f32) and hb (bf16)
// ---------------------------------------------------------------------------
__global__ void __launch_bounds__(256) embed_ln_kernel(
    const int* __restrict__ ids, const float* __restrict__ we,
    const float* __restrict__ pe, const float* __restrict__ te,
    const float* __restrict__ g, const float* __restrict__ bt,
    float* __restrict__ h, bf16* __restrict__ hb) {
    int token = blockIdx.x, tid = threadIdx.x;
    int s = token % SS;
    int id = ids[token];
    __shared__ float red[256];
    float x[3];
#pragma unroll
    for (int i = 0; i < 3; ++i) {
        int idx = tid + i * 256;
        x[i] = we[(size_t)id * HH + idx] + pe[(size_t)s * HH + idx] + te[idx];
    }
    float sum = block_reduce_sum(x[0] + x[1] + x[2], red, tid);
    float mu = sum * (1.0f / HH);
    float vs = 0.f;
#pragma unroll
    for (int i = 0; i < 3; ++i) { float d = x[i] - mu; vs += d * d; }
    vs = block_reduce_sum(vs, red, tid);
    float rstd = rsqrtf(vs * (1.0f / HH) + 1e-12f);
    size_t base = (size_t)token * HH;
#pragma unroll
    for (int i = 0; i < 3; ++i) {
        int idx = tid + i * 256;
        float v = (x[i] - mu) * rstd * g[idx] + bt[idx];
        h[base + idx] = v;
        hb[base + idx] = __float2bfloat16(v);
    }
}

// ---------------------------------------------------------------------------
// h = LN(h + proj + proj2)  -> h (f32) and hb (bf16)
// ---------------------------------------------------------------------------
__global__ void __launch_bounds__(256) add_ln_kernel(
    float* __restrict__ h, const float* __restrict__ proj,
    const float* __restrict__ proj2,
    const float* __restrict__ g, const float* __restrict__ bt,
    bf16* __restrict__ hb) {
    int token = blockIdx.x, tid = threadIdx.x;
    __shared__ float red[256];
    size_t base = (size_t)token * HH;
    float x[3];
#pragma unroll
    for (int i = 0; i < 3; ++i) {
        int idx = tid + i * 256;
        x[i] = h[base + idx] + proj[base + idx] + proj2[base + idx];
    }
    float sum = block_reduce_sum(x[0] + x[1] + x[2], red, tid);
    float mu = sum * (1.0f / HH);
    float vs = 0.f;
#pragma unroll
    for (int i = 0; i < 3; ++i) { float d = x[i] - mu; vs += d * d; }
    vs = block_reduce_sum(vs, red, tid);
    float rstd = rsqrtf(vs * (1.0f / HH) + 1e-12f);
#pragma unroll
    for (int i = 0; i < 3; ++i) {
        int idx = tid + i * 256;
        float v = (x[i] - mu) * rstd * g[idx] + bt[idx];
        h[base + idx] = v;
        hb[base + idx] = __float2bfloat16(v);
    }
}

// ---------------------------------------------------------------------------
// transpose-convert: in f32 [K][N] (row-major) -> out bf16 [N][K]
// ---------------------------------------------------------------------------
__global__ void __launch_bounds__(256) transp_conv(
    const float* __restrict__ in, bf16* __restrict__ out,
    int K, int N, size_t inStride, size_t outStride) {
    const float* src = in + (size_t)blockIdx.z * inStride;
    bf16* dst = out + (size_t)blockIdx.z * outStride;
    __shared__ float t[64][65];
    int n0 = blockIdx.x * 64, k0 = blockIdx.y * 64;
    int tid = threadIdx.x;
#pragma unroll
    for (int i = 0; i < 16; ++i) {
        int lin = tid + i * 256;
        int r = lin >> 6, c = lin & 63;
        int kk = k0 + r, nn = n0 + c;
        t[r][c] = (kk < K && nn < N) ? src[(size_t)kk * N + nn] : 0.f;
    }
    __syncthreads();
#pragma unroll
    for (int i = 0; i < 16; ++i) {
        int lin = tid + i * 256;
        int r = lin >> 6, c = lin & 63;
        int nn = n0 + r, kk = k0 + c;
        if (nn < N && kk < K)
            dst[(size_t)nn * K + kk] = __float2bfloat16(t[c][r]);
    }
}

// ---------------------------------------------------------------------------
// v slice of qkv [BS][ldv] bf16 -> vT [B][NH][DH][S] bf16
// ---------------------------------------------------------------------------
__global__ void __launch_bounds__(256) vtrans_kernel(const bf16* __restrict__ v,
                                                     bf16* __restrict__ vT,
                                                     int ldv) {
    __shared__ bf16 t[64][66];
    int s0 = blockIdx.x * 64, h = blockIdx.y, b = blockIdx.z;
    int tid = threadIdx.x;
#pragma unroll
    for (int i = 0; i < 16; ++i) {
        int lin = tid + i * 256;
        int sr = lin >> 6, dc = lin & 63;
        t[sr][dc] = v[((size_t)(b * SS + s0 + sr)) * ldv + h * 64 + dc];
    }
    __syncthreads();
#pragma unroll
    for (int i = 0; i < 16; ++i) {
        int lin = tid + i * 256;
        int dr = lin >> 6, sc = lin & 63;
        vT[(((size_t)(b * NHH + h)) * 64 + dr) * SS + s0 + sc] = t[sc][dr];
    }
}

// ---------------------------------------------------------------------------
// bf16 MFMA GEMM: C[M,N](ldc) = A[M,K](lda) @ BT[N,K](ldb)^T + bias
// 2-phase double-buffered pipeline: stage(t+1) issued before MFMA(t);
// one raw s_barrier + vmcnt(0) per K-step (staging latency hidden under MFMA).
// LDS 64B rows, slot swizzle: slot ^= (row>>1)&3  -> 2 lanes/bank (free).
// Swizzle applied to global SOURCE + fragment READ; LDS dest linear (rule 21).
// split-K over blockIdx.z (z>0: bias=0, out += z*zStride).
// ---------------------------------------------------------------------------
#define GBK 32

template <int TBM, int TBN, int OUT_BF16, int ACT>
__global__ void __launch_bounds__(256) gemm_bf16_kernel(
    const bf16* __restrict__ A, const bf16* __restrict__ BT,
    const float* __restrict__ bias, void* __restrict__ Cout,
    int M, int N, int K, int lda, int ldb, int ldc, size_t zStride) {
    constexpr int MFRAG = TBM / 32;
    constexpr int NFRAG = TBN / 32;
    constexpr int ABYTES = TBM * GBK * 2;
    constexpr int BBYTES = TBN * GBK * 2;
    __shared__ __align__(16) char As[2 * ABYTES];
    __shared__ __align__(16) char Bs[2 * BBYTES];
    int tid = threadIdx.x;
    int lane = tid & 63, wid = tid >> 6;

    int zz = blockIdx.z;
    const char* Ab = (const char*)(A + (size_t)zz * K);
    const char* Bb = (const char*)(BT + (size_t)zz * K);
    const float* biasz = (zz == 0) ? bias : nullptr;

    // T1: XCD-chunked swizzle (bijective when nwg%8==0)
    int nwg = gridDim.x * gridDim.y;
    int bid = blockIdx.y * gridDim.x + blockIdx.x;
    int swz = ((nwg & 7) == 0) ? ((bid & 7) * (nwg >> 3) + (bid >> 3)) : bid;
    int bx = swz % gridDim.x, by = swz / gridDim.x;
    int m0 = by * TBM, n0 = bx * TBN;
    int wr = (wid >> 1) * (TBM / 2), wc = (wid & 1) * (TBN / 2);

    f32x4 acc[MFRAG][NFRAG];
#pragma unroll
    for (int i = 0; i < MFRAG; ++i)
#pragma unroll
        for (int j = 0; j < NFRAG; ++j) acc[i][j] = Z4();

    auto stage = [&](int k0, int sel) {
#pragma unroll
        for (int i = 0; i < TBM / 64; ++i) {
            int lin = tid * 16 + i * 4096;
            int row = lin >> 6, slot = (lin >> 4) & 3;
            gload16(As + sel * ABYTES + lin,
                    Ab + ((size_t)(m0 + row) * lda + k0) * 2 +
                        ((slot ^ ((row >> 1) & 3)) << 4));
        }
#pragma unroll
        for (int i = 0; i < TBN / 64; ++i) {
            int lin = tid * 16 + i * 4096;
            int row = lin >> 6, slot = (lin >> 4) & 3;
            int nr = n0 + row; if (nr >= N) nr = N - 1;
            gload16(Bs + sel * BBYTES + lin,
                    Bb + ((size_t)nr * ldb + k0) * 2 +
                        ((slot ^ ((row >> 1) & 3)) << 4));
        }
    };

    const int T = K / GBK;
    stage(0, 0);
    wait_vm0_barrier();

    int cur = 0;
    for (int t = 0; t < T; ++t) {
        if (t + 1 < T) stage((t + 1) * GBK, cur ^ 1);

        const char* Ar = As + cur * ABYTES;
        const char* Br = Bs + cur * BBYTES;
        short8 af[MFRAG], bfr[NFRAG];
#pragma unroll
        for (int i = 0; i < MFRAG; ++i) {
            int ar = wr + i * 16 + (lane & 15);
            int slot = (lane >> 4) ^ ((ar >> 1) & 3);
            af[i] = *(const short8*)(Ar + ar * 64 + slot * 16);
        }
#pragma unroll
        for (int j = 0; j < NFRAG; ++j) {
            int br = wc + j * 16 + (lane & 15);
            int slot = (lane >> 4) ^ ((br >> 1) & 3);
            bfr[j] = *(const short8*)(Br + br * 64 + slot * 16);
        }
#pragma unroll
        for (int i = 0; i < MFRAG; ++i)
#pragma unroll
            for (int j = 0; j < NFRAG; ++j)
                acc[i][j] = __builtin_amdgcn_mfma_f32_16x16x32_bf16(
                    af[i], bfr[j], acc[i][j], 0, 0, 0);

        if (t + 1 < T) wait_vm0_barrier();
        cur ^= 1;
    }

    bool nfull = (n0 + TBN <= N);
#pragma unroll
    for (int i = 0; i < MFRAG; ++i) {
#pragma unroll
        for (int r = 0; r < 4; ++r) {
            int m = m0 + wr + i * 16 + (lane >> 4) * 4 + r;
#pragma unroll
            for (int j = 0; j < NFRAG; ++j) {
                int n = n0 + wc + j * 16 + (lane & 15);
                if (nfull || n < N) {
                    float v = acc[i][j][r] + (biasz ? biasz[n] : 0.f);
                    if (ACT) v = 0.5f * v * (1.0f + erff(v * 0.70710678118654752f));
                    if (OUT_BF16)
                        ((bf16*)Cout)[(size_t)m * ldc + n] = __float2bfloat16(v);
                    else
                        ((float*)Cout)[zz * zStride + (size_t)m * ldc + n] = v;
                }
            }
        }
    }
}

// ---------------------------------------------------------------------------
// flash attention, bf16 MFMA. Block = 64 q-rows (4 waves x 16), KV tiles of 64.
// K/V double-buffered; one raw barrier per tile (stage(t+1) hidden under
// QK/softmax/PV). P is per-wave LDS -> lgkmcnt(0) only, no barrier.
// LDS rows 128B, swizzle byte ^= (row&7)<<4.
// ---------------------------------------------------------------------------
__global__ void __launch_bounds__(256) attn_mfma_kernel(
    const bf16* __restrict__ Q, const bf16* __restrict__ K,
    const bf16* __restrict__ VT, const int* __restrict__ ids,
    const int* __restrict__ qlen, bf16* __restrict__ att, int ld) {
    __shared__ __align__(16) bf16 Qs[64 * 64];
    __shared__ __align__(16) bf16 Ks[2][64 * 64];
    __shared__ __align__(16) bf16 Vs[2][64 * 64];
    __shared__ __align__(16) bf16 Ps[4 * 16 * 64];
    __shared__ float padj[2][64];

    int tid = threadIdx.x, lane = tid & 63, w = tid >> 6;
    int q0 = blockIdx.x * 64, h = blockIdx.y, b = blockIdx.z;
    int ql = qlen[b];

    const char* kbase0 = (const char*)K + ((size_t)(b * SS) * ld) * 2;
    const char* vbase0 = (const char*)VT + (((size_t)(b * NHH + h)) * 64) * SS * 2;

    auto stageKV = [&](int kv0, int sel) {
        int lin = tid * 16;
#pragma unroll
        for (int i = 0; i < 2; ++i, lin += 4096) {
            int row = lin >> 7, bir = lin & 127;
            int sbir = bir ^ ((row & 7) << 4);
            gload16((char*)Ks[sel] + lin,
                    kbase0 + (size_t)(kv0 + row) * (ld * 2) + h * 128 + sbir);
            gload16((char*)Vs[sel] + lin,
                    vbase0 + (size_t)row * (SS * 2) + (size_t)kv0 * 2 + sbir);
        }
        if (tid < 64)
            padj[sel][tid] = (ids[b * SS + kv0 + tid] != PAD_ID) ? 1.f : 0.f;
    };

    // prologue: stage Q + first KV tile together
    {
        const char* qbase =
            (const char*)Q + ((size_t)(b * SS + q0) * ld) * 2 + h * 128;
        int lin = tid * 16;
#pragma unroll
        for (int i = 0; i < 2; ++i, lin += 4096) {
            int row = lin >> 7, bir = lin & 127;
            int sbir = bir ^ ((row & 7) << 4);
            gload16((char*)Qs + lin, qbase + (size_t)row * (ld * 2) + sbir);
        }
    }
    stageKV(0, 0);
    int qrow_base = q0 + w * 16 + (lane >> 4) * 4;   // + r
    bool padq[4];
#pragma unroll
    for (int r = 0; r < 4; ++r)
        padq[r] = (ids[b * SS + qrow_base + r] != PAD_ID);

    wait_vm0_lgkm0_barrier();

    // Q fragments stay in registers for the whole kernel
    short8 aq[2];
#pragma unroll
    for (int ks = 0; ks < 2; ++ks) {
        int row = w * 16 + (lane & 15);
        int bir = ks * 64 + (lane >> 4) * 16;
        aq[ks] = *(const short8*)((const char*)Qs + row * 128 +
                                  (bir ^ ((row & 7) << 4)));
    }

    float m_run[4], l_run[4];
    f32x4 accO[4];
#pragma unroll
    for (int r = 0; r < 4; ++r) { m_run[r] = -1e30f; l_run[r] = 0.f; }
#pragma unroll
    for (int d = 0; d < 4; ++d) accO[d] = Z4();

    int cur = 0;
    for (int kv0 = 0; kv0 < SS; kv0 += 64) {
        if (kv0 + 64 < SS) stageKV(kv0 + 64, cur ^ 1);
        const char* kb = (const char*)Ks[cur];
        const char* vb = (const char*)Vs[cur];

        // S = Q K^T  (rows=q, cols=kv)
        f32x4 accS[4];
        __builtin_amdgcn_s_setprio(1);
#pragma unroll
        for (int nf = 0; nf < 4; ++nf) {
            f32x4 z = Z4();
#pragma unroll
            for (int ks = 0; ks < 2; ++ks) {
                int row = nf * 16 + (lane & 15);
                int bir = ks * 64 + (lane >> 4) * 16;
                short8 bk = *(const short8*)(kb + row * 128 +
                                             (bir ^ ((row & 7) << 4)));
                z = __builtin_amdgcn_mfma_f32_16x16x32_bf16(aq[ks], bk, z, 0, 0, 0);
            }
            accS[nf] = z;
        }
        __builtin_amdgcn_s_setprio(0);

        // mask + scale + online softmax (per q-row = 16-lane groups)
        float p[4][4];        // [r][nf]
#pragma unroll
        for (int r = 0; r < 4; ++r) {
            int qg = qrow_base + r;
            float mx = -1e30f;
#pragma unroll
            for (int nf = 0; nf < 4; ++nf) {
                int j = kv0 + nf * 16 + (lane & 15);
                bool ok = padq[r] && (padj[cur][nf * 16 + (lane & 15)] != 0.f) &&
                          ((qg < ql) || (j < ql) || (j <= qg));
                float s = accS[nf][r] * 0.125f + (ok ? 0.f : -1e9f);
                p[r][nf] = s;
                mx = fmaxf(mx, s);
            }
#pragma unroll
            for (int off = 1; off < 16; off <<= 1)
                mx = fmaxf(mx, __shfl_xor(mx, off));
            float mnew = fmaxf(m_run[r], mx);
            float fac = __expf(m_run[r] - mnew);
            m_run[r] = mnew;
            float rs = 0.f;
#pragma unroll
            for (int nf = 0; nf < 4; ++nf) {
                float e = __expf(p[r][nf] - mnew);
                p[r][nf] = e;
                rs += e;
            }
#pragma unroll
            for (int off = 1; off < 16; off <<= 1)
                rs += __shfl_xor(rs, off);
            l_run[r] = l_run[r] * fac + rs;
#pragma unroll
            for (int df = 0; df < 4; ++df) accO[df][r] *= fac;
        }

        // write P (bf16) to per-wave LDS, swizzled; same-wave visibility only
#pragma unroll
        for (int r = 0; r < 4; ++r) {
            int prow = (lane >> 4) * 4 + r;
#pragma unroll
            for (int nf = 0; nf < 4; ++nf) {
                int c = nf * 16 + (lane & 15);
                int byte = (c * 2) ^ ((prow & 7) << 4);
                *(bf16*)((char*)Ps + w * 2048 + prow * 128 + byte) =
                    __float2bfloat16(p[r][nf]);
            }
        }
        asm volatile("s_waitcnt lgkmcnt(0)" ::: "memory");
        __builtin_amdgcn_sched_barrier(0);

        // O += P V  (contraction over kv)
        __builtin_amdgcn_s_setprio(1);
#pragma unroll
        for (int ks = 0; ks < 2; ++ks) {
            int prow = lane & 15;
            int bir = ks * 64 + (lane >> 4) * 16;
            short8 ap = *(const short8*)((const char*)Ps + w * 2048 + prow * 128 +
                                         (bir ^ ((prow & 7) << 4)));
#pragma unroll
            for (int df = 0; df < 4; ++df) {
                int vrow = df * 16 + (lane & 15);
                short8 bv = *(const short8*)(vb + vrow * 128 +
                                             (bir ^ ((vrow & 7) << 4)));
                accO[df] = __builtin_amdgcn_mfma_f32_16x16x32_bf16(
                    ap, bv, accO[df], 0, 0, 0);
            }
        }
        __builtin_amdgcn_s_setprio(0);

        if (kv0 + 64 < SS) wait_vm0_lgkm0_barrier();
        cur ^= 1;
    }

    // normalize + store
#pragma unroll
    for (int r = 0; r < 4; ++r) {
        int qg = qrow_base + r;
        float inv = 1.0f / l_run[r];
#pragma unroll
        for (int df = 0; df < 4; ++df) {
            int d = df * 16 + (lane & 15);
            att[((size_t)(b * SS) + qg) * HH + h * 64 + d] =
                __float2bfloat16(accO[df][r] * inv);
        }
    }
}

// ---------------------------------------------------------------------------
// launch
// ---------------------------------------------------------------------------
extern "C" void kernel_launch(void* const* d_in, const int* in_sizes, int n_in,
                              void* d_out, int out_size, void* d_ws, size_t ws_size,
                              hipStream_t stream) {
    const int*   ids      = (const int*)d_in[0];
    const float* word_emb = (const float*)d_in[1];
    const float* pos_emb  = (const float*)d_in[2];
    const float* type_emb = (const float*)d_in[3];
    const float* emb_ln_g = (const float*)d_in[4];
    const float* emb_ln_b = (const float*)d_in[5];
    const float* attn_w   = (const float*)d_in[6];
    const float* attn_b   = (const float*)d_in[7];
    const float* ln1_g    = (const float*)d_in[8];
    const float* ln1_b    = (const float*)d_in[9];
    const float* ffn_w1   = (const float*)d_in[10];
    const float* ffn_b1   = (const float*)d_in[11];
    const float* ffn_w2   = (const float*)d_in[12];
    const float* ffn_b2   = (const float*)d_in[13];
    const float* ln2_g    = (const float*)d_in[14];
    const float* ln2_b    = (const float*)d_in[15];
    const float* cls_w    = (const float*)d_in[16];
    const float* cls_b    = (const float*)d_in[17];
    float* out = (float*)d_out;

    // ---- workspace layout ----
    char* base = (char*)d_ws;
    size_t off = 0;
    auto take = [&](size_t bytes) {
        char* r = base + off;
        off += (bytes + 255) & ~(size_t)255;
        return r;
    };
    float* h    = (float*)take(BSH * 4);
    float* proj = (float*)take(2 * BSH * 4);      // proj + proj2 (split-K halves)
    bf16*  qkv  = (bf16*)take((size_t)BS * QKVN * 2);  // [BS][2304]
    bf16*  vT   = (bf16*)take(BSH * 2);
    bf16*  attb = (bf16*)take(BSH * 2);
    bf16*  ffb  = (bf16*)take(BSFF * 2);          // end of reusable span
    bf16*  hb   = (bf16*)take(BSH * 2);
    int*   qlen = (int*)take(256);
    size_t commonEnd = off;

    const size_t szAttnW = (size_t)48 * HH * HH * 2;
    const size_t szW1    = (size_t)LL * HH * FFF * 2;
    const size_t szCls   = (size_t)VV * HH * 2;
    const size_t fullNeed = commonEnd + szAttnW + 2 * szW1 + szCls;
    bool fullMode = (ws_size >= fullNeed);

    bf16 *wAttnT = nullptr, *w1T = nullptr, *w2T = nullptr, *clsT = nullptr, *wrot = nullptr;
    if (fullMode) {
        wAttnT = (bf16*)take(szAttnW);
        w1T    = (bf16*)take(szW1);
        w2T    = (bf16*)take(szW1);
        clsT   = (bf16*)take(szCls);
    } else {
        wrot = (bf16*)take((size_t)HH * FFF * 2);   // rotating buffer
        clsT = (bf16*)proj;                          // cls weight -> dead span
    }

    auto convw = [&](const float* src, bf16* dst, int K, int N) {
        dim3 g((N + 63) / 64, (K + 63) / 64, 1);
        transp_conv<<<g, 256, 0, stream>>>(src, dst, K, N, (size_t)0, (size_t)0);
    };

    qlen_kernel<<<BB, 256, 0, stream>>>(ids, qlen);

    if (fullMode) {
        transp_conv<<<dim3(12, 12, 48), 256, 0, stream>>>(
            attn_w, wAttnT, HH, HH, (size_t)HH * HH, (size_t)HH * HH);
        transp_conv<<<dim3(FFF / 64, HH / 64, LL), 256, 0, stream>>>(
            ffn_w1, w1T, HH, FFF, (size_t)HH * FFF, (size_t)HH * FFF);
        transp_conv<<<dim3(HH / 64, FFF / 64, LL), 256, 0, stream>>>(
            ffn_w2, w2T, FFF, HH, (size_t)HH * FFF, (size_t)HH * FFF);
        transp_conv<<<dim3((VV + 63) / 64, HH / 64, 1), 256, 0, stream>>>(
            cls_w, clsT, HH, VV, (size_t)0, (size_t)0);
    }

    embed_ln_kernel<<<BS, 256, 0, stream>>>(ids, word_emb, pos_emb, type_emb,
                                            emb_ln_g, emb_ln_b, h, hb);

    dim3 gQKV(QKVN / 128, BS / 128, 1);          // 576
    dim3 gWo(HH / 64, BS / 128, 2);              // 768 (split-K x2, K=384)
    dim3 gFF1(FFF / 128, BS / 128, 1);           // 768
    dim3 gFF2(HH / 64, BS / 128, 2);             // 768 (split-K x2, K=1536)
    dim3 gCls((VV + 127) / 128, BS / 128, 1);    // 5312
    dim3 gAttn(SS / 64, NHH, BB);
    dim3 gVT(SS / 64, NHH, BB);

    for (int l = 0; l < LL; ++l) {
        const float* wq32 = attn_w + (size_t)l * 4 * HH * HH;
        const float* wo32 = wq32 + (size_t)3 * HH * HH;
        const float* bqkv = attn_b + (size_t)l * 4 * HH;   // q,k,v contiguous
        const float* bo   = bqkv + 3 * HH;

        bf16 *wqkvT, *woT, *w1Tl, *w2Tl;
        if (fullMode) {
            wqkvT = wAttnT + (size_t)(l * 4) * HH * HH;    // [2304][768]
            woT   = wAttnT + (size_t)(l * 4 + 3) * HH * HH;
            w1Tl  = w1T + (size_t)l * HH * FFF;
            w2Tl  = w2T + (size_t)l * HH * FFF;
        } else {
            wqkvT = woT = w1Tl = w2Tl = wrot;
        }

        if (!fullMode) {
            convw(wq32, wrot, HH, HH);
            convw(wq32 + (size_t)HH * HH, wrot + (size_t)HH * HH, HH, HH);
            convw(wq32 + (size_t)2 * HH * HH, wrot + (size_t)2 * HH * HH, HH, HH);
        }
        gemm_bf16_kernel<128, 128, 1, 0><<<gQKV, 256, 0, stream>>>(
            hb, wqkvT, bqkv, qkv, BS, QKVN, HH, HH, HH, QKVN, 0);

        vtrans_kernel<<<gVT, 256, 0, stream>>>(qkv + 2 * HH, vT, QKVN);
        attn_mfma_kernel<<<gAttn, 256, 0, stream>>>(
            qkv, qkv + HH, vT, ids, qlen, attb, QKVN);

        if (!fullMode) convw(wo32, wrot, HH, HH);
        gemm_bf16_kernel<128, 64, 0, 0><<<gWo, 256, 0, stream>>>(
            attb, woT, bo, proj, BS, HH, HH / 2, HH, HH, HH, BSH);
        add_ln_kernel<<<BS, 256, 0, stream>>>(h, proj, proj + BSH,
                                              ln1_g + (size_t)l * HH,
                                              ln1_b + (size_t)l * HH, hb);

        if (!fullMode) convw(ffn_w1 + (size_t)l * HH * FFF, wrot, HH, FFF);
        gemm_bf16_kernel<128, 128, 1, 1><<<gFF1, 256, 0, stream>>>(
            hb, w1Tl, ffn_b1 + (size_t)l * FFF, ffb, BS, FFF, HH, HH, HH, FFF, 0);
        if (!fullMode) convw(ffn_w2 + (size_t)l * HH * FFF, wrot, FFF, HH);
        gemm_bf16_kernel<128, 64, 0, 0><<<gFF2, 256, 0, stream>>>(
            ffb, w2Tl, ffn_b2 + (size_t)l * HH, proj, BS, HH, FFF / 2, FFF, FFF,
            HH, BSH);
        add_ln_kernel<<<BS, 256, 0, stream>>>(h, proj, proj + BSH,
                                              ln2_g + (size_t)l * HH,
                                              ln2_b + (size_t)l * HH, hb);
    }

    if (!fullMode) convw(cls_w, clsT, HH, VV);
    gemm_bf16_kernel<128, 128, 0, 0><<<gCls, 256, 0, stream>>>(
        hb, clsT, cls_b, out, BS, VV, HH, HH, HH, VV, 0);
}